// Round 6
// baseline (268.115 us; speedup 1.0000x reference)
//
#include <hip/hip_runtime.h>
#include <hip/hip_bf16.h>

#define DMODEL 1024
#define NHEAD  16
#define DKD    64
#define BLK    128
#define TB     16
#define SCALEF 0.125f   // TAU / sqrt(DK)

typedef __attribute__((ext_vector_type(8))) short bf16x8;
typedef __attribute__((ext_vector_type(4))) float f32x4;

#define MFMA(A, B, C) __builtin_amdgcn_mfma_f32_16x16x32_bf16(A, B, C, 0, 0, 0)

union U8 { bf16x8 v; ushort u[8]; ushort2 u2[4]; ushort4 u4[2]; };

__device__ __forceinline__ ushort2 pk2(float a, float b) {
  union { __hip_bfloat162 h; ushort2 u; } c;
  c.h = __float22bfloat162_rn(make_float2(a, b));
  return c.u;
}
__device__ __forceinline__ ushort bfc(float x) {
  union { __hip_bfloat16 b; ushort u; } c;
  c.b = __float2bfloat16(x);
  return c.u;
}

// ---- LDS tile readers ----------------------------------------------------
// row tile [128][64], XOR-swizzled by ((r&7)<<3)
__device__ __forceinline__ bf16x8 frag64(const ushort* T, int r, int c) {
  return *reinterpret_cast<const bf16x8*>(T + ((r * 64 + c) ^ ((r & 7) << 3)));
}
// [128][128] tile, same swizzle
__device__ __forceinline__ bf16x8 frag128(const ushort* T, int r, int c) {
  return *reinterpret_cast<const bf16x8*>(T + ((r * 128 + c) ^ ((r & 7) << 3)));
}
// chunked transposed tile [64 d][128 r]: elem (d,r) at
// (r>>2)*256 + ((d*4) ^ (((d>>4)&3)<<2)) + (r&3)   -- conflict-free R/W
__device__ __forceinline__ bf16x8 fragT2(const ushort* T, int d, int r0) {
  const int base = (r0 >> 2) * 256 + ((d * 4) ^ (((d >> 4) & 3) << 2));
  U8 x;
  x.u4[0] = *reinterpret_cast<const ushort4*>(T + base);
  x.u4[1] = *reinterpret_cast<const ushort4*>(T + base + 256);
  return x.v;
}
// global row-major -> register fragment (8 consecutive fp32)
__device__ __forceinline__ bf16x8 gfrag(const float* __restrict__ g, float sc) {
  const float4 fa = *reinterpret_cast<const float4*>(g);
  const float4 fb = *reinterpret_cast<const float4*>(g + 4);
  U8 x;
  x.u2[0] = pk2(fa.x * sc, fa.y * sc);
  x.u2[1] = pk2(fa.z * sc, fa.w * sc);
  x.u2[2] = pk2(fb.x * sc, fb.y * sc);
  x.u2[3] = pk2(fb.z * sc, fb.w * sc);
  return x.v;
}

// ---- staging (512 threads) -----------------------------------------------
__device__ __forceinline__ void issue4(const float* __restrict__ g, int tid, float4* f) {
#pragma unroll
  for (int it = 0; it < 4; ++it) {
    const int idx = tid + 512 * it;
    f[it] = *reinterpret_cast<const float4*>(g + (idx >> 4) * DMODEL + 4 * (idx & 15));
  }
}
__device__ __forceinline__ void wrow(ushort* T, const float4* f, float sc, int tid) {
#pragma unroll
  for (int it = 0; it < 4; ++it) {
    const int idx = tid + 512 * it;
    const int r = idx >> 4, d4 = idx & 15;
    const ushort2 lo = pk2(f[it].x * sc, f[it].y * sc);
    const ushort2 hi = pk2(f[it].z * sc, f[it].w * sc);
    ushort4 u; u.x = lo.x; u.y = lo.y; u.z = hi.x; u.w = hi.y;
    *reinterpret_cast<ushort4*>(T + ((r * 64 + 4 * d4) ^ ((r & 7) << 3))) = u;
  }
}
// 4x4 shfl butterfly transpose -> chunked T tile (conflict-free writes)
__device__ __forceinline__ void wchunk(ushort* T, const float4* f, float sc, int tid) {
  const int a = (tid >> 4) & 3;
#pragma unroll
  for (int it = 0; it < 4; ++it) {
    const int idx = tid + 512 * it;
    const int r = idx >> 4, d4 = idx & 15;
    const float w0 = f[it].x * sc, w1 = f[it].y * sc, w2 = f[it].z * sc, w3 = f[it].w * sc;
    const float s0 = __shfl_xor(w1, 16), s1 = __shfl_xor(w0, 16);
    const float s2 = __shfl_xor(w3, 16), s3 = __shfl_xor(w2, 16);
    const float u0 = (a & 1) ? s0 : w0;
    const float u1 = (a & 1) ? w1 : s1;
    const float u2 = (a & 1) ? s2 : w2;
    const float u3 = (a & 1) ? w3 : s3;
    const float t0 = __shfl_xor(u2, 32), t1 = __shfl_xor(u3, 32);
    const float t2 = __shfl_xor(u0, 32), t3 = __shfl_xor(u1, 32);
    const float z0 = (a & 2) ? t0 : u0;
    const float z1 = (a & 2) ? t1 : u1;
    const float z2 = (a & 2) ? u2 : t2;
    const float z3 = (a & 2) ? u3 : t3;
    const int d = 4 * d4 + a, R0 = r - a;   // lane holds rows R0..R0+3 of col d
    const ushort2 lo = pk2(z0, z1);
    const ushort2 hi = pk2(z2, z3);
    ushort4 o; o.x = lo.x; o.y = lo.y; o.z = hi.x; o.w = hi.y;
    *reinterpret_cast<ushort4*>(T + (R0 >> 2) * 256 + ((d * 4) ^ (((d >> 4) & 3) << 2))) = o;
  }
}

// ---- fused kernel --------------------------------------------------------
// One block per (h, i-block, j-parity) = 512 blocks total (decode is
// bijective: xcd(3b) | h-parity(1b) | ib(4b) | par(1b) -- R5's bug was a
// 1024-block launch that ran every tuple twice).
// Computes S/dA/softmax/dS ONCE per active pair; dQ accumulated in regs
// (atomicAdd at end); dK/dV contributions atomicAdd'd per iteration
// (outputs pre-zeroed by hipMemsetAsync). LDS 80 KB -> 2 blocks/CU.
__global__ void __launch_bounds__(512, 4)
bwd_fused(const float* __restrict__ q, const float* __restrict__ kk,
          const float* __restrict__ v, const float* __restrict__ dOg,
          const int* __restrict__ mask,
          float* __restrict__ dQ, float* __restrict__ dK, float* __restrict__ dV) {
  __shared__ ushort sm[40960];
  ushort* kR = sm;
  ushort* vR = sm + 8192;
  ushort* kT = sm + 16384;
  ushort* qT = sm + 24576;
  ushort* oT = sm + 32768;
  ushort* X  = sm;             // overlays kR+vR
  const int tid = threadIdx.x;
  const int l = tid & 63, l15 = l & 15, lg = (l >> 4) & 3;
  const int w = tid >> 6, pw = w * 16;
  const int bid = blockIdx.x;
  // XCD-local decode: xcd = bid&7 hosts heads {2*xcd, 2*xcd+1}
  const int xcd = bid & 7, idx = bid >> 3;      // idx: 6 bits (grid = 512)
  const int h   = (xcd << 1) | (idx & 1);
  const int ib  = (idx >> 1) & 15;
  const int par = (idx >> 5) & 1;
  const f32x4 zz = {0.f, 0.f, 0.f, 0.f};

  unsigned bm = 0;
  for (int t = par; t < TB; t += 2)
    if (mask[ib * TB + t]) bm |= 1u << t;

  f32x4 accQ[4] = {zz, zz, zz, zz};

  if (bm) {
    const float* qbase = q   + (size_t)(ib * BLK) * DMODEL + h * DKD;
    const float* obase = dOg + (size_t)(ib * BLK) * DMODEL + h * DKD;
    // persistent stage-1 A-fragments (i-invariant)
    bf16x8 aq[2], ao[2];
#pragma unroll
    for (int kb = 0; kb < 2; ++kb) {
      const size_t row = (size_t)(ib * BLK + pw + l15) * DMODEL + h * DKD + kb * 32 + lg * 8;
      aq[kb] = gfrag(q + row, 1.f);
      ao[kb] = gfrag(dOg + row, 1.f);
    }
    // stage qT/oT once (first read is P7/P5, many barriers later)
    {
      float4 tf[4];
      issue4(qbase, tid, tf); wchunk(qT, tf, SCALEF, tid);
      issue4(obase, tid, tf); wchunk(oT, tf, 1.f, tid);
    }
    int j = __ffs(bm) - 1;
    unsigned rest = bm & (bm - 1);
    float4 kf[4], vf[4];
    issue4(kk + (size_t)(j * BLK) * DMODEL + h * DKD, tid, kf);
    issue4(v  + (size_t)(j * BLK) * DMODEL + h * DKD, tid, vf);
    wrow(kR, kf, SCALEF, tid);
    wchunk(kT, kf, SCALEF, tid);
    wrow(vR, vf, 1.f, tid);
    __syncthreads();                                   // barA

    while (j >= 0) {
      const int jn = rest ? (__ffs(rest) - 1) : -1;
      rest = rest ? (rest & (rest - 1)) : 0u;

      // ---- P1: S = q.k^T, dA = dO.v^T ; softmax ; dS ----
      // lane holds S[p = pw + lg*4 + r][c = nf*16 + l15]
      f32x4 S[8], dA[8];
#pragma unroll
      for (int nf = 0; nf < 8; ++nf) { S[nf] = zz; dA[nf] = zz; }
#pragma unroll
      for (int kb = 0; kb < 2; ++kb) {
        const int ck = kb * 32 + lg * 8;
#pragma unroll
        for (int nf = 0; nf < 8; ++nf) {
          S[nf]  = MFMA(aq[kb], frag64(kR, nf * 16 + l15, ck), S[nf]);
          dA[nf] = MFMA(ao[kb], frag64(vR, nf * 16 + l15, ck), dA[nf]);
        }
      }
#pragma unroll
      for (int r = 0; r < 4; ++r) {
        float mx = -1e30f;
#pragma unroll
        for (int nf = 0; nf < 8; ++nf) mx = fmaxf(mx, S[nf][r]);
        mx = fmaxf(mx, __shfl_xor(mx, 1));
        mx = fmaxf(mx, __shfl_xor(mx, 2));
        mx = fmaxf(mx, __shfl_xor(mx, 4));
        mx = fmaxf(mx, __shfl_xor(mx, 8));
        float ss = 0.f;
#pragma unroll
        for (int nf = 0; nf < 8; ++nf) { const float e = __expf(S[nf][r] - mx); S[nf][r] = e; ss += e; }
        ss += __shfl_xor(ss, 1); ss += __shfl_xor(ss, 2);
        ss += __shfl_xor(ss, 4); ss += __shfl_xor(ss, 8);
        const float inv = 1.f / (ss + 1e-12f);
        float rd = 0.f;
#pragma unroll
        for (int nf = 0; nf < 8; ++nf) { const float pn = S[nf][r] * inv; S[nf][r] = pn; rd += pn * dA[nf][r]; }
        rd += __shfl_xor(rd, 1); rd += __shfl_xor(rd, 2);
        rd += __shfl_xor(rd, 4); rd += __shfl_xor(rd, 8);
#pragma unroll
        for (int nf = 0; nf < 8; ++nf) dA[nf][r] = S[nf][r] * (dA[nf][r] - rd);
      }
      __syncthreads();                                 // barB (kR/vR reads done)

      // ---- P2: X = dS[p][c] (scalar b16, conflict-light) ----
#pragma unroll
      for (int nf = 0; nf < 8; ++nf) {
        const int c = nf * 16 + l15;
#pragma unroll
        for (int r = 0; r < 4; ++r) {
          const int p = pw + lg * 4 + r;
          X[(p * 128 + c) ^ ((p & 7) << 3)] = bfc(dA[nf][r]);
        }
      }
      __syncthreads();                                 // barC

      // ---- P3: dQ += dS @ k  (A = X rows p, B = kT) ----
#pragma unroll
      for (int kc = 0; kc < 4; ++kc) {
        const int cc = kc * 32 + lg * 8;
        const bf16x8 a = frag128(X, pw + l15, cc);
#pragma unroll
        for (int nfd = 0; nfd < 4; ++nfd)
          accQ[nfd] = MFMA(a, fragT2(kT, nfd * 16 + l15, cc), accQ[nfd]);
      }
      __syncthreads();                                 // barD

      // ---- P4: X = Pn^T[c][p] (b64 packs) ----
#pragma unroll
      for (int nf = 0; nf < 8; ++nf) {
        const int c = nf * 16 + l15;
        const ushort2 lo = pk2(S[nf][0], S[nf][1]);
        const ushort2 hi = pk2(S[nf][2], S[nf][3]);
        ushort4 u; u.x = lo.x; u.y = lo.y; u.z = hi.x; u.w = hi.y;
        *reinterpret_cast<ushort4*>(X + ((c * 128 + pw + 4 * lg) ^ ((c & 7) << 3))) = u;
      }
      __syncthreads();                                 // barE

      // ---- P5: dV contribution = Pn^T @ dO -> atomicAdd ----
      {
        f32x4 c4[4] = {zz, zz, zz, zz};
#pragma unroll
        for (int kp = 0; kp < 4; ++kp) {
          const int pp = kp * 32 + lg * 8;
          const bf16x8 a = frag128(X, pw + l15, pp);
#pragma unroll
          for (int nfd = 0; nfd < 4; ++nfd)
            c4[nfd] = MFMA(a, fragT2(oT, nfd * 16 + l15, pp), c4[nfd]);
        }
#pragma unroll
        for (int nfd = 0; nfd < 4; ++nfd)
#pragma unroll
          for (int r = 0; r < 4; ++r)
            atomicAdd(&dV[(size_t)(j * BLK + pw + lg * 4 + r) * DMODEL + h * DKD + nfd * 16 + l15],
                      c4[nfd][r]);
      }
      __syncthreads();                                 // barF

      // ---- P6: X = dS^T[c][p]; prefetch next k/v ----
#pragma unroll
      for (int nf = 0; nf < 8; ++nf) {
        const int c = nf * 16 + l15;
        const ushort2 lo = pk2(dA[nf][0], dA[nf][1]);
        const ushort2 hi = pk2(dA[nf][2], dA[nf][3]);
        ushort4 u; u.x = lo.x; u.y = lo.y; u.z = hi.x; u.w = hi.y;
        *reinterpret_cast<ushort4*>(X + ((c * 128 + pw + 4 * lg) ^ ((c & 7) << 3))) = u;
      }
      if (jn >= 0) {
        issue4(kk + (size_t)(jn * BLK) * DMODEL + h * DKD, tid, kf);
        issue4(v  + (size_t)(jn * BLK) * DMODEL + h * DKD, tid, vf);
      }
      __syncthreads();                                 // barG

      // ---- P7: dK contribution = dS^T @ q -> atomicAdd (q pre-scaled) ----
      {
        f32x4 c4[4] = {zz, zz, zz, zz};
#pragma unroll
        for (int kp = 0; kp < 4; ++kp) {
          const int pp = kp * 32 + lg * 8;
          const bf16x8 a = frag128(X, pw + l15, pp);
#pragma unroll
          for (int nfd = 0; nfd < 4; ++nfd)
            c4[nfd] = MFMA(a, fragT2(qT, nfd * 16 + l15, pp), c4[nfd]);
        }
#pragma unroll
        for (int nfd = 0; nfd < 4; ++nfd)
#pragma unroll
          for (int r = 0; r < 4; ++r)
            atomicAdd(&dK[(size_t)(j * BLK + pw + lg * 4 + r) * DMODEL + h * DKD + nfd * 16 + l15],
                      c4[nfd][r]);
      }
      __syncthreads();                                 // barH (X free)

      // ---- P0: write next k/v tiles ----
      if (jn >= 0) {
        wrow(kR, kf, SCALEF, tid);
        wchunk(kT, kf, SCALEF, tid);
        wrow(vR, vf, 1.f, tid);
        __syncthreads();                               // barA
      }
      j = jn;
    }

    // dQ flush (par-sibling also contributes -> atomicAdd onto zeroed buffer)
#pragma unroll
    for (int nfd = 0; nfd < 4; ++nfd)
#pragma unroll
      for (int r = 0; r < 4; ++r)
        atomicAdd(&dQ[(size_t)(ib * BLK + pw + lg * 4 + r) * DMODEL + h * DKD + nfd * 16 + l15],
                  accQ[nfd][r]);
  }
}

extern "C" void kernel_launch(void* const* d_in, const int* in_sizes, int n_in,
                              void* d_out, int out_size, void* d_ws, size_t ws_size,
                              hipStream_t stream) {
  const float* q  = (const float*)d_in[0];
  const float* k  = (const float*)d_in[1];
  const float* v  = (const float*)d_in[2];
  const float* dO = (const float*)d_in[3];
  const int* mask = (const int*)d_in[4];
  float* out = (float*)d_out;
  float* dQ = out;
  float* dK = out + (size_t)2048 * DMODEL;
  float* dV = out + (size_t)2 * 2048 * DMODEL;

  hipMemsetAsync(d_out, 0, (size_t)out_size * sizeof(float), stream);
  bwd_fused<<<2 * NHEAD * TB, 512, 0, stream>>>(q, k, v, dO, mask, dQ, dK, dV);
}

// Round 7
// 226.025 us; speedup vs baseline: 1.1862x; 1.1862x over previous
//
#include <hip/hip_runtime.h>
#include <hip/hip_bf16.h>

#define DMODEL 1024
#define NHEAD  16
#define DKD    64
#define BLK    128
#define TB     16
#define SCALEF 0.125f   // TAU / sqrt(DK)

typedef __attribute__((ext_vector_type(8))) short bf16x8;
typedef __attribute__((ext_vector_type(4))) float f32x4;

#define MFMA(A, B, C) __builtin_amdgcn_mfma_f32_16x16x32_bf16(A, B, C, 0, 0, 0)

union U8 { bf16x8 v; ushort u[8]; ushort2 u2[4]; ushort4 u4[2]; };

__device__ __forceinline__ ushort2 pk2(float a, float b) {
  union { __hip_bfloat162 h; ushort2 u; } c;
  c.h = __float22bfloat162_rn(make_float2(a, b));
  return c.u;
}

// ---- LDS tile readers (R2/R6-proven) -------------------------------------
// row tile [128][64], XOR-swizzled by ((r&7)<<3)
__device__ __forceinline__ bf16x8 frag64(const ushort* T, int r, int c) {
  return *reinterpret_cast<const bf16x8*>(T + ((r * 64 + c) ^ ((r & 7) << 3)));
}
// [128][128] tile, same swizzle
__device__ __forceinline__ bf16x8 frag128(const ushort* T, int r, int c) {
  return *reinterpret_cast<const bf16x8*>(T + ((r * 128 + c) ^ ((r & 7) << 3)));
}
// chunked transposed tile [64 d][128 r]: elem (d,r) at
// (r>>2)*256 + ((d*4) ^ (((d>>4)&3)<<2)) + (r&3)  -- conflict-free R/W
__device__ __forceinline__ bf16x8 fragT2(const ushort* T, int d, int r0) {
  const int base = (r0 >> 2) * 256 + ((d * 4) ^ (((d >> 4) & 3) << 2));
  U8 x;
  x.u4[0] = *reinterpret_cast<const ushort4*>(T + base);
  x.u4[1] = *reinterpret_cast<const ushort4*>(T + base + 256);
  return x.v;
}
// global row-major -> register fragment (8 consecutive fp32)
__device__ __forceinline__ bf16x8 gfrag(const float* __restrict__ g, float sc) {
  const float4 fa = *reinterpret_cast<const float4*>(g);
  const float4 fb = *reinterpret_cast<const float4*>(g + 4);
  U8 x;
  x.u2[0] = pk2(fa.x * sc, fa.y * sc);
  x.u2[1] = pk2(fa.z * sc, fa.w * sc);
  x.u2[2] = pk2(fb.x * sc, fb.y * sc);
  x.u2[3] = pk2(fb.z * sc, fb.w * sc);
  return x.v;
}

// ---- staging straight from global (512 threads) --------------------------
__device__ __forceinline__ void gwrow(ushort* T, const float* __restrict__ g,
                                      float sc, int tid) {
#pragma unroll
  for (int it = 0; it < 4; ++it) {
    const int idx = tid + 512 * it;
    const int r = idx >> 4, d4 = idx & 15;
    const float4 f = *reinterpret_cast<const float4*>(g + r * DMODEL + 4 * d4);
    const ushort2 lo = pk2(f.x * sc, f.y * sc);
    const ushort2 hi = pk2(f.z * sc, f.w * sc);
    ushort4 u; u.x = lo.x; u.y = lo.y; u.z = hi.x; u.w = hi.y;
    *reinterpret_cast<ushort4*>(T + ((r * 64 + 4 * d4) ^ ((r & 7) << 3))) = u;
  }
}
// 4x4 shfl butterfly transpose -> chunked T tile (conflict-free writes)
__device__ __forceinline__ void gwchunk(ushort* T, const float* __restrict__ g,
                                        float sc, int tid) {
  const int a = (tid >> 4) & 3;
#pragma unroll
  for (int it = 0; it < 4; ++it) {
    const int idx = tid + 512 * it;
    const int r = idx >> 4, d4 = idx & 15;
    const float4 f = *reinterpret_cast<const float4*>(g + r * DMODEL + 4 * d4);
    const float w0 = f.x * sc, w1 = f.y * sc, w2 = f.z * sc, w3 = f.w * sc;
    const float s0 = __shfl_xor(w1, 16), s1 = __shfl_xor(w0, 16);
    const float s2 = __shfl_xor(w3, 16), s3 = __shfl_xor(w2, 16);
    const float u0 = (a & 1) ? s0 : w0;
    const float u1 = (a & 1) ? w1 : s1;
    const float u2 = (a & 1) ? s2 : w2;
    const float u3 = (a & 1) ? w3 : s3;
    const float t0 = __shfl_xor(u2, 32), t1 = __shfl_xor(u3, 32);
    const float t2 = __shfl_xor(u0, 32), t3 = __shfl_xor(u1, 32);
    const float z0 = (a & 2) ? t0 : u0;
    const float z1 = (a & 2) ? t1 : u1;
    const float z2 = (a & 2) ? u2 : t2;
    const float z3 = (a & 2) ? u3 : t3;
    const int d = 4 * d4 + a, R0 = r - a;   // lane holds rows R0..R0+3 of col d
    const ushort2 lo = pk2(z0, z1);
    const ushort2 hi = pk2(z2, z3);
    ushort4 o; o.x = lo.x; o.y = lo.y; o.z = hi.x; o.w = hi.y;
    *reinterpret_cast<ushort4*>(T + (R0 >> 2) * 256 + ((d * 4) ^ (((d >> 4) & 3) << 2))) = o;
  }
}

// ---- two-role kernel, no atomics, 64 KB LDS -> 2 blocks/CU ----------------
// grid 512: xcd(3b) | hpar(1b) | role(1b) | blk(4b)
// role 0 (dQ, owns (h,ib)): kR=0 vR=8192 kT=16384 ; X overlays kR+vR
// role 1 (dK/dV, owns (h,jb)): kR=0 vR=8192 qT=16384 oT=24576 ; X overlays kR+vR
__global__ void __launch_bounds__(512, 4)
bwd_roles(const float* __restrict__ q, const float* __restrict__ kk,
          const float* __restrict__ v, const float* __restrict__ dOg,
          const int* __restrict__ mask,
          float* __restrict__ dQ, float* __restrict__ dK, float* __restrict__ dV) {
  __shared__ ushort sm[32768];
  ushort* kR = sm;
  ushort* vR = sm + 8192;
  ushort* X  = sm;            // overlays kR+vR ([128][128] bf16)
  const int tid = threadIdx.x;
  const int l = tid & 63, l15 = l & 15, lg = (l >> 4) & 3;
  const int w = tid >> 6, pw = w * 16;
  const int bid = blockIdx.x;
  const int xcd = bid & 7, idx = bid >> 3;
  const int h    = (xcd << 1) | (idx & 1);
  const int role = (idx >> 1) & 1;
  const int blk  = (idx >> 2) & 15;
  const f32x4 zz = {0.f, 0.f, 0.f, 0.f};

  if (role == 0) {
    // ================= dQ for (h, ib = blk) =================
    ushort* kT = sm + 16384;
    unsigned bm = 0;
    for (int t = 0; t < TB; ++t)
      if (mask[blk * TB + t]) bm |= 1u << t;

    // loop-invariant B-fragments (q, dO rows of this i-block) in registers
    bf16x8 bq[2], bo[2];
#pragma unroll
    for (int kb = 0; kb < 2; ++kb) {
      const size_t row = (size_t)(blk * BLK + pw + l15) * DMODEL + h * DKD + kb * 32 + lg * 8;
      bq[kb] = gfrag(q + row, 1.f);
      bo[kb] = gfrag(dOg + row, 1.f);
    }
    f32x4 accQ[4] = {zz, zz, zz, zz};

    if (bm) {
      int j = __ffs(bm) - 1;
      unsigned rest = bm & (bm - 1);
      gwrow(kR, kk + (size_t)(j * BLK) * DMODEL + h * DKD, SCALEF, tid);
      gwchunk(kT, kk + (size_t)(j * BLK) * DMODEL + h * DKD, SCALEF, tid);
      gwrow(vR, v + (size_t)(j * BLK) * DMODEL + h * DKD, 1.f, tid);
      __syncthreads();                                 // barA

      while (j >= 0) {
        const int jn = rest ? (__ffs(rest) - 1) : -1;
        rest = rest ? (rest & (rest - 1)) : 0u;

        // S^T = k.q^T, dA^T = v.dO^T ; lane: p = pw+l15, c = mf*16+lg*4+r
        f32x4 ST[8], dAT[8];
#pragma unroll
        for (int mf = 0; mf < 8; ++mf) { ST[mf] = zz; dAT[mf] = zz; }
#pragma unroll
        for (int kb = 0; kb < 2; ++kb) {
          const int ck = kb * 32 + lg * 8;
#pragma unroll
          for (int mf = 0; mf < 8; ++mf) {
            ST[mf]  = MFMA(frag64(kR, mf * 16 + l15, ck), bq[kb], ST[mf]);
            dAT[mf] = MFMA(frag64(vR, mf * 16 + l15, ck), bo[kb], dAT[mf]);
          }
        }
        // per-p softmax over 128 c (regs + lanes l^16, l^32)
        float mx = -1e30f;
#pragma unroll
        for (int mf = 0; mf < 8; ++mf)
#pragma unroll
          for (int r = 0; r < 4; ++r) mx = fmaxf(mx, ST[mf][r]);
        mx = fmaxf(mx, __shfl_xor(mx, 16));
        mx = fmaxf(mx, __shfl_xor(mx, 32));
        float ss = 0.f;
#pragma unroll
        for (int mf = 0; mf < 8; ++mf)
#pragma unroll
          for (int r = 0; r < 4; ++r) { const float e = __expf(ST[mf][r] - mx); ST[mf][r] = e; ss += e; }
        ss += __shfl_xor(ss, 16);
        ss += __shfl_xor(ss, 32);
        const float inv = 1.f / (ss + 1e-12f);
        float rd = 0.f;
#pragma unroll
        for (int mf = 0; mf < 8; ++mf)
#pragma unroll
          for (int r = 0; r < 4; ++r) { const float pn = ST[mf][r] * inv; ST[mf][r] = pn; rd += pn * dAT[mf][r]; }
        rd += __shfl_xor(rd, 16);
        rd += __shfl_xor(rd, 32);
#pragma unroll
        for (int mf = 0; mf < 8; ++mf)
#pragma unroll
          for (int r = 0; r < 4; ++r) dAT[mf][r] = ST[mf][r] * (dAT[mf][r] - rd);
        __syncthreads();                               // barB (kR/vR reads done)

        // write dS[p][c] into X (b64 packs; 4 consecutive c in regs)
        const int p = pw + l15;
#pragma unroll
        for (int mf = 0; mf < 8; ++mf) {
          const ushort2 lo = pk2(dAT[mf][0], dAT[mf][1]);
          const ushort2 hi = pk2(dAT[mf][2], dAT[mf][3]);
          ushort4 u; u.x = lo.x; u.y = lo.y; u.z = hi.x; u.w = hi.y;
          *reinterpret_cast<ushort4*>(X + ((p * 128 + mf * 16 + 4 * lg) ^ ((p & 7) << 3))) = u;
        }
        __syncthreads();                               // barC

        // dQ += dS @ k  (A = X rows p, B = kT chunked)
#pragma unroll
        for (int kc = 0; kc < 4; ++kc) {
          const int cc = kc * 32 + lg * 8;
          const bf16x8 a = frag128(X, pw + l15, cc);
#pragma unroll
          for (int nfd = 0; nfd < 4; ++nfd)
            accQ[nfd] = MFMA(a, fragT2(kT, nfd * 16 + l15, cc), accQ[nfd]);
        }
        __syncthreads();                               // barD (X/kT reads done)

        if (jn >= 0) {
          gwrow(kR, kk + (size_t)(jn * BLK) * DMODEL + h * DKD, SCALEF, tid);
          gwchunk(kT, kk + (size_t)(jn * BLK) * DMODEL + h * DKD, SCALEF, tid);
          gwrow(vR, v + (size_t)(jn * BLK) * DMODEL + h * DKD, 1.f, tid);
          __syncthreads();                             // barA
        }
        j = jn;
      }
    }
#pragma unroll
    for (int nfd = 0; nfd < 4; ++nfd)
#pragma unroll
      for (int r = 0; r < 4; ++r)
        dQ[(size_t)(blk * BLK + pw + lg * 4 + r) * DMODEL + h * DKD + nfd * 16 + l15] =
            accQ[nfd][r];

  } else {
    // ================= dK, dV for (h, jb = blk) =================
    ushort* qT = sm + 16384;
    ushort* oT = sm + 24576;
    const int jb = blk;
    unsigned bm = 0;
    for (int t = 0; t < TB; ++t)
      if (mask[t * TB + jb]) bm |= 1u << t;

    f32x4 accK[4] = {zz, zz, zz, zz};
    f32x4 accV[4] = {zz, zz, zz, zz};

    if (bm) {
      int i = __ffs(bm) - 1;
      unsigned rest = bm & (bm - 1);
      gwrow(kR, kk + (size_t)(jb * BLK) * DMODEL + h * DKD, SCALEF, tid);
      gwrow(vR, v + (size_t)(jb * BLK) * DMODEL + h * DKD, 1.f, tid);
      gwchunk(qT, q + (size_t)(i * BLK) * DMODEL + h * DKD, SCALEF, tid);
      gwchunk(oT, dOg + (size_t)(i * BLK) * DMODEL + h * DKD, 1.f, tid);
      __syncthreads();                                 // barA

      while (i >= 0) {
        const int in = rest ? (__ffs(rest) - 1) : -1;
        rest = rest ? (rest & (rest - 1)) : 0u;

        // A-fragments for current i (L2-hot strided reads)
        bf16x8 aq[2], ao[2];
#pragma unroll
        for (int kb = 0; kb < 2; ++kb) {
          const size_t row = (size_t)(i * BLK + pw + l15) * DMODEL + h * DKD + kb * 32 + lg * 8;
          aq[kb] = gfrag(q + row, 1.f);
          ao[kb] = gfrag(dOg + row, 1.f);
        }

        // S = q.k^T, dA = dO.v^T ; lane: p = pw+lg*4+r, c = nf*16+l15
        f32x4 S[8], dA[8];
#pragma unroll
        for (int nf = 0; nf < 8; ++nf) { S[nf] = zz; dA[nf] = zz; }
#pragma unroll
        for (int kb = 0; kb < 2; ++kb) {
          const int ck = kb * 32 + lg * 8;
#pragma unroll
          for (int nf = 0; nf < 8; ++nf) {
            S[nf]  = MFMA(aq[kb], frag64(kR, nf * 16 + l15, ck), S[nf]);
            dA[nf] = MFMA(ao[kb], frag64(vR, nf * 16 + l15, ck), dA[nf]);
          }
        }
        // softmax over c per row; dS = Pn*(dA - rowdot)
#pragma unroll
        for (int r = 0; r < 4; ++r) {
          float mx = -1e30f;
#pragma unroll
          for (int nf = 0; nf < 8; ++nf) mx = fmaxf(mx, S[nf][r]);
          mx = fmaxf(mx, __shfl_xor(mx, 1));
          mx = fmaxf(mx, __shfl_xor(mx, 2));
          mx = fmaxf(mx, __shfl_xor(mx, 4));
          mx = fmaxf(mx, __shfl_xor(mx, 8));
          float ss = 0.f;
#pragma unroll
          for (int nf = 0; nf < 8; ++nf) { const float e = __expf(S[nf][r] - mx); S[nf][r] = e; ss += e; }
          ss += __shfl_xor(ss, 1); ss += __shfl_xor(ss, 2);
          ss += __shfl_xor(ss, 4); ss += __shfl_xor(ss, 8);
          const float inv = 1.f / (ss + 1e-12f);
          float rd = 0.f;
#pragma unroll
          for (int nf = 0; nf < 8; ++nf) { const float pn = S[nf][r] * inv; S[nf][r] = pn; rd += pn * dA[nf][r]; }
          rd += __shfl_xor(rd, 1); rd += __shfl_xor(rd, 2);
          rd += __shfl_xor(rd, 4); rd += __shfl_xor(rd, 8);
#pragma unroll
          for (int nf = 0; nf < 8; ++nf) dA[nf][r] = S[nf][r] * (dA[nf][r] - rd);
        }
        __syncthreads();                               // barB (kR/vR reads done)

        // write Pn^T [c][p] into X (b64 packs; 4 consecutive p in regs)
#pragma unroll
        for (int nf = 0; nf < 8; ++nf) {
          const int c = nf * 16 + l15;
          const ushort2 lo = pk2(S[nf][0], S[nf][1]);
          const ushort2 hi = pk2(S[nf][2], S[nf][3]);
          ushort4 u; u.x = lo.x; u.y = lo.y; u.z = hi.x; u.w = hi.y;
          *reinterpret_cast<ushort4*>(X + ((c * 128 + pw + 4 * lg) ^ ((c & 7) << 3))) = u;
        }
        __syncthreads();                               // barC

        // dV += Pn^T @ dO  (A = X rows c, B = oT chunked)
#pragma unroll
        for (int kp = 0; kp < 4; ++kp) {
          const int pp = kp * 32 + lg * 8;
          const bf16x8 a = frag128(X, pw + l15, pp);
#pragma unroll
          for (int nfd = 0; nfd < 4; ++nfd)
            accV[nfd] = MFMA(a, fragT2(oT, nfd * 16 + l15, pp), accV[nfd]);
        }
        __syncthreads();                               // barD (X PnT reads done)

        // write dS^T [c][p] into X
#pragma unroll
        for (int nf = 0; nf < 8; ++nf) {
          const int c = nf * 16 + l15;
          const ushort2 lo = pk2(dA[nf][0], dA[nf][1]);
          const ushort2 hi = pk2(dA[nf][2], dA[nf][3]);
          ushort4 u; u.x = lo.x; u.y = lo.y; u.z = hi.x; u.w = hi.y;
          *reinterpret_cast<ushort4*>(X + ((c * 128 + pw + 4 * lg) ^ ((c & 7) << 3))) = u;
        }
        __syncthreads();                               // barE

        // dK += dS^T @ q  (A = X rows c, B = qT chunked; q pre-scaled)
#pragma unroll
        for (int kp = 0; kp < 4; ++kp) {
          const int pp = kp * 32 + lg * 8;
          const bf16x8 a = frag128(X, pw + l15, pp);
#pragma unroll
          for (int nfd = 0; nfd < 4; ++nfd)
            accK[nfd] = MFMA(a, fragT2(qT, nfd * 16 + l15, pp), accK[nfd]);
        }
        __syncthreads();                               // barF (X/qT/oT reads done)

        // restage k/v (X destroyed them) and next qT/oT
        gwrow(kR, kk + (size_t)(jb * BLK) * DMODEL + h * DKD, SCALEF, tid);
        gwrow(vR, v + (size_t)(jb * BLK) * DMODEL + h * DKD, 1.f, tid);
        if (in >= 0) {
          gwchunk(qT, q + (size_t)(in * BLK) * DMODEL + h * DKD, SCALEF, tid);
          gwchunk(oT, dOg + (size_t)(in * BLK) * DMODEL + h * DKD, 1.f, tid);
        }
        if (in >= 0) __syncthreads();                  // barA
        i = in;
      }
    }
#pragma unroll
    for (int nfd = 0; nfd < 4; ++nfd)
#pragma unroll
      for (int r = 0; r < 4; ++r) {
        const size_t rowo = (size_t)(jb * BLK + pw + lg * 4 + r) * DMODEL + h * DKD + nfd * 16 + l15;
        dK[rowo] = accK[nfd][r];
        dV[rowo] = accV[nfd][r];
      }
  }
}

extern "C" void kernel_launch(void* const* d_in, const int* in_sizes, int n_in,
                              void* d_out, int out_size, void* d_ws, size_t ws_size,
                              hipStream_t stream) {
  const float* q  = (const float*)d_in[0];
  const float* k  = (const float*)d_in[1];
  const float* v  = (const float*)d_in[2];
  const float* dO = (const float*)d_in[3];
  const int* mask = (const int*)d_in[4];
  float* out = (float*)d_out;
  float* dQ = out;
  float* dK = out + (size_t)2048 * DMODEL;
  float* dV = out + (size_t)2 * 2048 * DMODEL;

  bwd_roles<<<2 * NHEAD * TB, 512, 0, stream>>>(q, k, v, dO, mask, dQ, dK, dV);
}

// Round 8
// 174.420 us; speedup vs baseline: 1.5372x; 1.2959x over previous
//
#include <hip/hip_runtime.h>
#include <hip/hip_bf16.h>

#define DMODEL 1024
#define NHEAD  16
#define DKD    64
#define BLK    128
#define TB     16
#define SCALEF 0.125f   // TAU / sqrt(DK)

typedef __attribute__((ext_vector_type(8))) short bf16x8;
typedef __attribute__((ext_vector_type(4))) float f32x4;

#define MFMA(A, B, C) __builtin_amdgcn_mfma_f32_16x16x32_bf16(A, B, C, 0, 0, 0)

union U8 { bf16x8 v; ushort u[8]; ushort2 u2[4]; ushort4 u4[2]; };

__device__ __forceinline__ ushort2 pk2(float a, float b) {
  union { __hip_bfloat162 h; ushort2 u; } c;
  c.h = __float22bfloat162_rn(make_float2(a, b));
  return c.u;
}

// ---- readers of the tile images (R2/R6/R7-proven formulas) ---------------
// row tile [128][64], XOR-swizzled by ((r&7)<<3)
__device__ __forceinline__ bf16x8 frag64(const ushort* T, int r, int c) {
  return *reinterpret_cast<const bf16x8*>(T + ((r * 64 + c) ^ ((r & 7) << 3)));
}
// [128][128] tile, same swizzle
__device__ __forceinline__ bf16x8 frag128(const ushort* T, int r, int c) {
  return *reinterpret_cast<const bf16x8*>(T + ((r * 128 + c) ^ ((r & 7) << 3)));
}
// chunked transposed tile [64 d][128 r]: elem (d,r) at
// (r>>2)*256 + ((d*4) ^ (((d>>4)&3)<<2)) + (r&3)  -- conflict-free R/W
__device__ __forceinline__ bf16x8 fragT2(const ushort* T, int d, int r0) {
  const int base = (r0 >> 2) * 256 + ((d * 4) ^ (((d >> 4) & 3) << 2));
  U8 x;
  x.u4[0] = *reinterpret_cast<const ushort4*>(T + base);
  x.u4[1] = *reinterpret_cast<const ushort4*>(T + base + 256);
  return x.v;
}
// global fp32 row-major -> register fragment (8 consecutive fp32)
__device__ __forceinline__ bf16x8 gfrag(const float* __restrict__ g, float sc) {
  const float4 fa = *reinterpret_cast<const float4*>(g);
  const float4 fb = *reinterpret_cast<const float4*>(g + 4);
  U8 x;
  x.u2[0] = pk2(fa.x * sc, fa.y * sc);
  x.u2[1] = pk2(fa.z * sc, fa.w * sc);
  x.u2[2] = pk2(fb.x * sc, fb.y * sc);
  x.u2[3] = pk2(fb.z * sc, fb.w * sc);
  return x.v;
}

// ---- image writers (512 threads; dst may be global (prepass) or LDS) -----
__device__ __forceinline__ void gwrow(ushort* T, const float* __restrict__ g,
                                      float sc, int tid) {
#pragma unroll
  for (int it = 0; it < 4; ++it) {
    const int idx = tid + 512 * it;
    const int r = idx >> 4, d4 = idx & 15;
    const float4 f = *reinterpret_cast<const float4*>(g + r * DMODEL + 4 * d4);
    const ushort2 lo = pk2(f.x * sc, f.y * sc);
    const ushort2 hi = pk2(f.z * sc, f.w * sc);
    ushort4 u; u.x = lo.x; u.y = lo.y; u.z = hi.x; u.w = hi.y;
    *reinterpret_cast<ushort4*>(T + ((r * 64 + 4 * d4) ^ ((r & 7) << 3))) = u;
  }
}
// 4x4 shfl butterfly transpose -> chunked T image (conflict-free writes)
__device__ __forceinline__ void gwchunk(ushort* T, const float* __restrict__ g,
                                        float sc, int tid) {
  const int a = (tid >> 4) & 3;
#pragma unroll
  for (int it = 0; it < 4; ++it) {
    const int idx = tid + 512 * it;
    const int r = idx >> 4, d4 = idx & 15;
    const float4 f = *reinterpret_cast<const float4*>(g + r * DMODEL + 4 * d4);
    const float w0 = f.x * sc, w1 = f.y * sc, w2 = f.z * sc, w3 = f.w * sc;
    const float s0 = __shfl_xor(w1, 16), s1 = __shfl_xor(w0, 16);
    const float s2 = __shfl_xor(w3, 16), s3 = __shfl_xor(w2, 16);
    const float u0 = (a & 1) ? s0 : w0;
    const float u1 = (a & 1) ? w1 : s1;
    const float u2 = (a & 1) ? s2 : w2;
    const float u3 = (a & 1) ? w3 : s3;
    const float t0 = __shfl_xor(u2, 32), t1 = __shfl_xor(u3, 32);
    const float t2 = __shfl_xor(u0, 32), t3 = __shfl_xor(u1, 32);
    const float z0 = (a & 2) ? t0 : u0;
    const float z1 = (a & 2) ? t1 : u1;
    const float z2 = (a & 2) ? u2 : t2;
    const float z3 = (a & 2) ? u3 : t3;
    const int d = 4 * d4 + a, R0 = r - a;   // lane holds rows R0..R0+3 of col d
    const ushort2 lo = pk2(z0, z1);
    const ushort2 hi = pk2(z2, z3);
    ushort4 o; o.x = lo.x; o.y = lo.y; o.z = hi.x; o.w = hi.y;
    *reinterpret_cast<ushort4*>(T + (R0 >> 2) * 256 + ((d * 4) ^ (((d >> 4) & 3) << 2))) = o;
  }
}

// ---- prepass: fp32 inputs -> bf16 LDS-ready images in d_ws ----------------
// per (h,t): IMG 0 = KR (k row, *SCALEF), 1 = VR (v row), 2 = KT (k chunked,
// *SCALEF), 3 = QT (q chunked, *SCALEF), 4 = OT (dO chunked). 16 KB each.
#define IMG(h, t, i) (ws + (((size_t)(h) * TB + (t)) * 5 + (i)) * 8192)

__global__ void __launch_bounds__(512, 2)
prepass(const float* __restrict__ q, const float* __restrict__ kk,
        const float* __restrict__ v, const float* __restrict__ dOg,
        ushort* __restrict__ ws) {
  const int bid = blockIdx.x;          // 256 = h*16 + t
  const int h = bid >> 4, t = bid & 15;
  const int tid = threadIdx.x;
  const size_t off = (size_t)(t * BLK) * DMODEL + h * DKD;
  gwrow  (IMG(h, t, 0), kk + off, SCALEF, tid);
  gwrow  (IMG(h, t, 1), v  + off, 1.f,    tid);
  gwchunk(IMG(h, t, 2), kk + off, SCALEF, tid);
  gwchunk(IMG(h, t, 3), q  + off, SCALEF, tid);
  gwchunk(IMG(h, t, 4), dOg + off, 1.f,   tid);
}

// pure memcpy staging: 16 KB image -> LDS (verbatim; layout already baked)
__device__ __forceinline__ void cpy16k(ushort* dst, const ushort* src, int tid) {
  const uint4* s = reinterpret_cast<const uint4*>(src);
  uint4* d = reinterpret_cast<uint4*>(dst);
  d[tid] = s[tid];
  d[tid + 512] = s[tid + 512];
}

// ---- main kernel: two roles, no atomics, 64 KB LDS -> 2 blocks/CU ---------
// grid 512: xcd(3b) | hpar(1b) | role(1b) | blk(4b)
// LDS map (ushorts): kR=0 vR=8192 A=16384 (kT | qT) B=24576 (oT) ; X overlays kR+vR
__global__ void __launch_bounds__(512, 4)
bwd_roles(const float* __restrict__ q, const float* __restrict__ dOg,
          const ushort* __restrict__ ws, const int* __restrict__ mask,
          float* __restrict__ dQ, float* __restrict__ dK, float* __restrict__ dV) {
  __shared__ ushort sm[32768];
  ushort* kR = sm;
  ushort* vR = sm + 8192;
  ushort* X  = sm;            // overlays kR+vR ([128][128] bf16)
  const int tid = threadIdx.x;
  const int l = tid & 63, l15 = l & 15, lg = (l >> 4) & 3;
  const int w = tid >> 6, pw = w * 16;
  const int bid = blockIdx.x;
  const int xcd = bid & 7, idx = bid >> 3;
  const int h    = (xcd << 1) | (idx & 1);
  const int role = (idx >> 1) & 1;
  const int blk  = (idx >> 2) & 15;
  const f32x4 zz = {0.f, 0.f, 0.f, 0.f};

  if (role == 0) {
    // ================= dQ for (h, ib = blk) =================
    ushort* kT = sm + 16384;
    unsigned bm = 0;
    for (int t = 0; t < TB; ++t)
      if (mask[blk * TB + t]) bm |= 1u << t;

    // loop-invariant B-fragments (q, dO rows of this i-block) in registers
    bf16x8 bq[2], bo[2];
#pragma unroll
    for (int kb = 0; kb < 2; ++kb) {
      const size_t row = (size_t)(blk * BLK + pw + l15) * DMODEL + h * DKD + kb * 32 + lg * 8;
      bq[kb] = gfrag(q + row, 1.f);
      bo[kb] = gfrag(dOg + row, 1.f);
    }
    f32x4 accQ[4] = {zz, zz, zz, zz};

    if (bm) {
      int j = __ffs(bm) - 1;
      unsigned rest = bm & (bm - 1);
      cpy16k(kR, IMG(h, j, 0), tid);
      cpy16k(vR, IMG(h, j, 1), tid);
      cpy16k(kT, IMG(h, j, 2), tid);
      __syncthreads();                                 // barA

      while (j >= 0) {
        const int jn = rest ? (__ffs(rest) - 1) : -1;
        rest = rest ? (rest & (rest - 1)) : 0u;

        // S^T = k.q^T, dA^T = v.dO^T ; lane: p = pw+l15, c = mf*16+lg*4+r
        f32x4 ST[8], dAT[8];
#pragma unroll
        for (int mf = 0; mf < 8; ++mf) { ST[mf] = zz; dAT[mf] = zz; }
#pragma unroll
        for (int kb = 0; kb < 2; ++kb) {
          const int ck = kb * 32 + lg * 8;
#pragma unroll
          for (int mf = 0; mf < 8; ++mf) {
            ST[mf]  = MFMA(frag64(kR, mf * 16 + l15, ck), bq[kb], ST[mf]);
            dAT[mf] = MFMA(frag64(vR, mf * 16 + l15, ck), bo[kb], dAT[mf]);
          }
        }
        // per-p softmax over 128 c (regs + lanes l^16, l^32)
        float mx = -1e30f;
#pragma unroll
        for (int mf = 0; mf < 8; ++mf)
#pragma unroll
          for (int r = 0; r < 4; ++r) mx = fmaxf(mx, ST[mf][r]);
        mx = fmaxf(mx, __shfl_xor(mx, 16));
        mx = fmaxf(mx, __shfl_xor(mx, 32));
        float ss = 0.f;
#pragma unroll
        for (int mf = 0; mf < 8; ++mf)
#pragma unroll
          for (int r = 0; r < 4; ++r) { const float e = __expf(ST[mf][r] - mx); ST[mf][r] = e; ss += e; }
        ss += __shfl_xor(ss, 16);
        ss += __shfl_xor(ss, 32);
        const float inv = 1.f / (ss + 1e-12f);
        float rd = 0.f;
#pragma unroll
        for (int mf = 0; mf < 8; ++mf)
#pragma unroll
          for (int r = 0; r < 4; ++r) { const float pn = ST[mf][r] * inv; ST[mf][r] = pn; rd += pn * dAT[mf][r]; }
        rd += __shfl_xor(rd, 16);
        rd += __shfl_xor(rd, 32);
#pragma unroll
        for (int mf = 0; mf < 8; ++mf)
#pragma unroll
          for (int r = 0; r < 4; ++r) dAT[mf][r] = ST[mf][r] * (dAT[mf][r] - rd);
        __syncthreads();                               // barB (kR/vR reads done)

        // write dS[p][c] into X (b64 packs)
        const int p = pw + l15;
#pragma unroll
        for (int mf = 0; mf < 8; ++mf) {
          const ushort2 lo = pk2(dAT[mf][0], dAT[mf][1]);
          const ushort2 hi = pk2(dAT[mf][2], dAT[mf][3]);
          ushort4 u; u.x = lo.x; u.y = lo.y; u.z = hi.x; u.w = hi.y;
          *reinterpret_cast<ushort4*>(X + ((p * 128 + mf * 16 + 4 * lg) ^ ((p & 7) << 3))) = u;
        }
        __syncthreads();                               // barC

        // dQ += dS @ k  (A = X rows p, B = kT chunked)
#pragma unroll
        for (int kc = 0; kc < 4; ++kc) {
          const int cc = kc * 32 + lg * 8;
          const bf16x8 a = frag128(X, pw + l15, cc);
#pragma unroll
          for (int nfd = 0; nfd < 4; ++nfd)
            accQ[nfd] = MFMA(a, fragT2(kT, nfd * 16 + l15, cc), accQ[nfd]);
        }
        __syncthreads();                               // barD (X/kT reads done)

        if (jn >= 0) {
          cpy16k(kR, IMG(h, jn, 0), tid);
          cpy16k(vR, IMG(h, jn, 1), tid);
          cpy16k(kT, IMG(h, jn, 2), tid);
          __syncthreads();                             // barA
        }
        j = jn;
      }
    }
#pragma unroll
    for (int nfd = 0; nfd < 4; ++nfd)
#pragma unroll
      for (int r = 0; r < 4; ++r)
        dQ[(size_t)(blk * BLK + pw + lg * 4 + r) * DMODEL + h * DKD + nfd * 16 + l15] =
            accQ[nfd][r];

  } else {
    // ================= dK, dV for (h, jb = blk) =================
    ushort* qT = sm + 16384;
    ushort* oT = sm + 24576;
    const int jb = blk;
    unsigned bm = 0;
    for (int t = 0; t < TB; ++t)
      if (mask[t * TB + jb]) bm |= 1u << t;

    f32x4 accK[4] = {zz, zz, zz, zz};
    f32x4 accV[4] = {zz, zz, zz, zz};

    if (bm) {
      int i = __ffs(bm) - 1;
      unsigned rest = bm & (bm - 1);
      cpy16k(kR, IMG(h, jb, 0), tid);
      cpy16k(vR, IMG(h, jb, 1), tid);
      cpy16k(qT, IMG(h, i, 3), tid);
      cpy16k(oT, IMG(h, i, 4), tid);
      __syncthreads();                                 // barA

      while (i >= 0) {
        const int in = rest ? (__ffs(rest) - 1) : -1;
        rest = rest ? (rest & (rest - 1)) : 0u;

        // A-fragments for current i (fp32 global, L2-hot)
        bf16x8 aq[2], ao[2];
#pragma unroll
        for (int kb = 0; kb < 2; ++kb) {
          const size_t row = (size_t)(i * BLK + pw + l15) * DMODEL + h * DKD + kb * 32 + lg * 8;
          aq[kb] = gfrag(q + row, 1.f);
          ao[kb] = gfrag(dOg + row, 1.f);
        }

        // S = q.k^T, dA = dO.v^T ; lane: p = pw+lg*4+r, c = nf*16+l15
        f32x4 S[8], dA[8];
#pragma unroll
        for (int nf = 0; nf < 8; ++nf) { S[nf] = zz; dA[nf] = zz; }
#pragma unroll
        for (int kb = 0; kb < 2; ++kb) {
          const int ck = kb * 32 + lg * 8;
#pragma unroll
          for (int nf = 0; nf < 8; ++nf) {
            S[nf]  = MFMA(aq[kb], frag64(kR, nf * 16 + l15, ck), S[nf]);
            dA[nf] = MFMA(ao[kb], frag64(vR, nf * 16 + l15, ck), dA[nf]);
          }
        }
        // softmax over c per row; dS = Pn*(dA - rowdot)
#pragma unroll
        for (int r = 0; r < 4; ++r) {
          float mx = -1e30f;
#pragma unroll
          for (int nf = 0; nf < 8; ++nf) mx = fmaxf(mx, S[nf][r]);
          mx = fmaxf(mx, __shfl_xor(mx, 1));
          mx = fmaxf(mx, __shfl_xor(mx, 2));
          mx = fmaxf(mx, __shfl_xor(mx, 4));
          mx = fmaxf(mx, __shfl_xor(mx, 8));
          float ss = 0.f;
#pragma unroll
          for (int nf = 0; nf < 8; ++nf) { const float e = __expf(S[nf][r] - mx); S[nf][r] = e; ss += e; }
          ss += __shfl_xor(ss, 1); ss += __shfl_xor(ss, 2);
          ss += __shfl_xor(ss, 4); ss += __shfl_xor(ss, 8);
          const float inv = 1.f / (ss + 1e-12f);
          float rd = 0.f;
#pragma unroll
          for (int nf = 0; nf < 8; ++nf) { const float pn = S[nf][r] * inv; S[nf][r] = pn; rd += pn * dA[nf][r]; }
          rd += __shfl_xor(rd, 1); rd += __shfl_xor(rd, 2);
          rd += __shfl_xor(rd, 4); rd += __shfl_xor(rd, 8);
#pragma unroll
          for (int nf = 0; nf < 8; ++nf) dA[nf][r] = S[nf][r] * (dA[nf][r] - rd);
        }
        __syncthreads();                               // barB (kR/vR reads done)

        // write Pn^T [c][p] into X (b64 packs)
#pragma unroll
        for (int nf = 0; nf < 8; ++nf) {
          const int c = nf * 16 + l15;
          const ushort2 lo = pk2(S[nf][0], S[nf][1]);
          const ushort2 hi = pk2(S[nf][2], S[nf][3]);
          ushort4 u; u.x = lo.x; u.y = lo.y; u.z = hi.x; u.w = hi.y;
          *reinterpret_cast<ushort4*>(X + ((c * 128 + pw + 4 * lg) ^ ((c & 7) << 3))) = u;
        }
        __syncthreads();                               // barC

        // dV += Pn^T @ dO  (A = X rows c, B = oT chunked)
#pragma unroll
        for (int kp = 0; kp < 4; ++kp) {
          const int pp = kp * 32 + lg * 8;
          const bf16x8 a = frag128(X, pw + l15, pp);
#pragma unroll
          for (int nfd = 0; nfd < 4; ++nfd)
            accV[nfd] = MFMA(a, fragT2(oT, nfd * 16 + l15, pp), accV[nfd]);
        }
        __syncthreads();                               // barD (X PnT reads done)

        // write dS^T [c][p] into X
#pragma unroll
        for (int nf = 0; nf < 8; ++nf) {
          const int c = nf * 16 + l15;
          const ushort2 lo = pk2(dA[nf][0], dA[nf][1]);
          const ushort2 hi = pk2(dA[nf][2], dA[nf][3]);
          ushort4 u; u.x = lo.x; u.y = lo.y; u.z = hi.x; u.w = hi.y;
          *reinterpret_cast<ushort4*>(X + ((c * 128 + pw + 4 * lg) ^ ((c & 7) << 3))) = u;
        }
        __syncthreads();                               // barE

        // dK += dS^T @ q  (A = X rows c, B = qT chunked; q pre-scaled)
#pragma unroll
        for (int kp = 0; kp < 4; ++kp) {
          const int pp = kp * 32 + lg * 8;
          const bf16x8 a = frag128(X, pw + l15, pp);
#pragma unroll
          for (int nfd = 0; nfd < 4; ++nfd)
            accK[nfd] = MFMA(a, fragT2(qT, nfd * 16 + l15, pp), accK[nfd]);
        }
        __syncthreads();                               // barF (X/qT/oT reads done)

        if (in >= 0) {
          cpy16k(kR, IMG(h, jb, 0), tid);   // L2-hot (same image every iter)
          cpy16k(vR, IMG(h, jb, 1), tid);
          cpy16k(qT, IMG(h, in, 3), tid);
          cpy16k(oT, IMG(h, in, 4), tid);
          __syncthreads();                             // barA
        }
        i = in;
      }
    }
#pragma unroll
    for (int nfd = 0; nfd < 4; ++nfd)
#pragma unroll
      for (int r = 0; r < 4; ++r) {
        const size_t rowo = (size_t)(jb * BLK + pw + lg * 4 + r) * DMODEL + h * DKD + nfd * 16 + l15;
        dK[rowo] = accK[nfd][r];
        dV[rowo] = accV[nfd][r];
      }
  }
}

extern "C" void kernel_launch(void* const* d_in, const int* in_sizes, int n_in,
                              void* d_out, int out_size, void* d_ws, size_t ws_size,
                              hipStream_t stream) {
  const float* q  = (const float*)d_in[0];
  const float* k  = (const float*)d_in[1];
  const float* v  = (const float*)d_in[2];
  const float* dO = (const float*)d_in[3];
  const int* mask = (const int*)d_in[4];
  float* out = (float*)d_out;
  float* dQ = out;
  float* dK = out + (size_t)2048 * DMODEL;
  float* dV = out + (size_t)2 * 2048 * DMODEL;
  ushort* ws = (ushort*)d_ws;   // needs 16*16*5*16KB = 20 MB

  prepass<<<NHEAD * TB, 512, 0, stream>>>(q, k, v, dO, ws);
  bwd_roles<<<2 * NHEAD * TB, 512, 0, stream>>>(q, dO, ws, mask, dQ, dK, dV);
}

// Round 9
// 120.437 us; speedup vs baseline: 2.2262x; 1.4482x over previous
//
#include <hip/hip_runtime.h>
#include <hip/hip_bf16.h>

#define DMODEL 1024
#define NHEAD  16
#define DKD    64
#define BLK    128
#define TB     16
#define SCALEF 0.125f   // TAU / sqrt(DK)

typedef __attribute__((ext_vector_type(8))) short bf16x8;
typedef __attribute__((ext_vector_type(4))) float f32x4;
typedef __attribute__((ext_vector_type(4))) unsigned int ui4;

#define MFMA(A, B, C) __builtin_amdgcn_mfma_f32_16x16x32_bf16(A, B, C, 0, 0, 0)

union U8 { bf16x8 v; ushort u[8]; ushort2 u2[4]; ushort4 u4[2]; };

__device__ __forceinline__ ushort2 pk2(float a, float b) {
  union { __hip_bfloat162 h; ushort2 u; } c;
  c.h = __float22bfloat162_rn(make_float2(a, b));
  return c.u;
}

// ---- tile-image readers (R2/R6/R7-proven formulas) -----------------------
// row tile [128][64], XOR-swizzled by ((r&7)<<3)
__device__ __forceinline__ bf16x8 frag64(const ushort* T, int r, int c) {
  return *reinterpret_cast<const bf16x8*>(T + ((r * 64 + c) ^ ((r & 7) << 3)));
}
// same formula but from GLOBAL image, non-temporal (single-use data)
__device__ __forceinline__ bf16x8 frag64g(const ushort* T, int r, int c) {
  return __builtin_nontemporal_load(
      reinterpret_cast<const bf16x8*>(T + ((r * 64 + c) ^ ((r & 7) << 3))));
}
// [128][128] tile, same swizzle
__device__ __forceinline__ bf16x8 frag128(const ushort* T, int r, int c) {
  return *reinterpret_cast<const bf16x8*>(T + ((r * 128 + c) ^ ((r & 7) << 3)));
}
// chunked transposed tile [64 d][128 r]: elem (d,r) at
// (r>>2)*256 + ((d*4) ^ (((d>>4)&3)<<2)) + (r&3)  -- conflict-free R/W
__device__ __forceinline__ bf16x8 fragT2(const ushort* T, int d, int r0) {
  const int base = (r0 >> 2) * 256 + ((d * 4) ^ (((d >> 4) & 3) << 2));
  U8 x;
  x.u4[0] = *reinterpret_cast<const ushort4*>(T + base);
  x.u4[1] = *reinterpret_cast<const ushort4*>(T + base + 256);
  return x.v;
}
// global fp32 row-major -> register fragment (8 consecutive fp32)
__device__ __forceinline__ bf16x8 gfrag(const float* __restrict__ g, float sc) {
  const float4 fa = *reinterpret_cast<const float4*>(g);
  const float4 fb = *reinterpret_cast<const float4*>(g + 4);
  U8 x;
  x.u2[0] = pk2(fa.x * sc, fa.y * sc);
  x.u2[1] = pk2(fa.z * sc, fa.w * sc);
  x.u2[2] = pk2(fb.x * sc, fb.y * sc);
  x.u2[3] = pk2(fb.z * sc, fb.w * sc);
  return x.v;
}

// ---- image writers (prepass; 512 threads) --------------------------------
__device__ __forceinline__ void gwrow(ushort* T, const float* __restrict__ g,
                                      float sc, int tid) {
#pragma unroll
  for (int it = 0; it < 4; ++it) {
    const int idx = tid + 512 * it;
    const int r = idx >> 4, d4 = idx & 15;
    const float4 f = *reinterpret_cast<const float4*>(g + r * DMODEL + 4 * d4);
    const ushort2 lo = pk2(f.x * sc, f.y * sc);
    const ushort2 hi = pk2(f.z * sc, f.w * sc);
    ushort4 u; u.x = lo.x; u.y = lo.y; u.z = hi.x; u.w = hi.y;
    *reinterpret_cast<ushort4*>(T + ((r * 64 + 4 * d4) ^ ((r & 7) << 3))) = u;
  }
}
// 4x4 shfl butterfly transpose -> chunked T image (conflict-free writes)
__device__ __forceinline__ void gwchunk(ushort* T, const float* __restrict__ g,
                                        float sc, int tid) {
  const int a = (tid >> 4) & 3;
#pragma unroll
  for (int it = 0; it < 4; ++it) {
    const int idx = tid + 512 * it;
    const int r = idx >> 4, d4 = idx & 15;
    const float4 f = *reinterpret_cast<const float4*>(g + r * DMODEL + 4 * d4);
    const float w0 = f.x * sc, w1 = f.y * sc, w2 = f.z * sc, w3 = f.w * sc;
    const float s0 = __shfl_xor(w1, 16), s1 = __shfl_xor(w0, 16);
    const float s2 = __shfl_xor(w3, 16), s3 = __shfl_xor(w2, 16);
    const float u0 = (a & 1) ? s0 : w0;
    const float u1 = (a & 1) ? w1 : s1;
    const float u2 = (a & 1) ? s2 : w2;
    const float u3 = (a & 1) ? w3 : s3;
    const float t0 = __shfl_xor(u2, 32), t1 = __shfl_xor(u3, 32);
    const float t2 = __shfl_xor(u0, 32), t3 = __shfl_xor(u1, 32);
    const float z0 = (a & 2) ? t0 : u0;
    const float z1 = (a & 2) ? t1 : u1;
    const float z2 = (a & 2) ? u2 : t2;
    const float z3 = (a & 2) ? u3 : t3;
    const int d = 4 * d4 + a, R0 = r - a;
    const ushort2 lo = pk2(z0, z1);
    const ushort2 hi = pk2(z2, z3);
    ushort4 o; o.x = lo.x; o.y = lo.y; o.z = hi.x; o.w = hi.y;
    *reinterpret_cast<ushort4*>(T + (R0 >> 2) * 256 + ((d * 4) ^ (((d >> 4) & 3) << 2))) = o;
  }
}

// images per (h,t): 0 KR(k*scale) 1 VR(v) 2 KT(k*scale) 3 QT(q*scale) 4 OT(dO)
//                   5 QR(q) 6 OR(dO)   (5/6 only if ws large enough)
__device__ __forceinline__ ushort* IMGp(ushort* ws, int imgN, int h, int t, int i) {
  return ws + (((size_t)h * TB + t) * imgN + i) * 8192;
}
__device__ __forceinline__ const ushort* IMGc(const ushort* ws, int imgN, int h, int t, int i) {
  return ws + (((size_t)h * TB + t) * imgN + i) * 8192;
}

__global__ void __launch_bounds__(512, 2)
prepass(const float* __restrict__ q, const float* __restrict__ kk,
        const float* __restrict__ v, const float* __restrict__ dOg,
        ushort* __restrict__ ws, int imgN) {
  const int bid = blockIdx.x;          // 256 = h*16 + t
  const int h = bid >> 4, t = bid & 15;
  const int tid = threadIdx.x;
  const size_t off = (size_t)(t * BLK) * DMODEL + h * DKD;
  gwrow  (IMGp(ws, imgN, h, t, 0), kk + off, SCALEF, tid);
  gwrow  (IMGp(ws, imgN, h, t, 1), v  + off, 1.f,    tid);
  gwchunk(IMGp(ws, imgN, h, t, 2), kk + off, SCALEF, tid);
  gwchunk(IMGp(ws, imgN, h, t, 3), q  + off, SCALEF, tid);
  gwchunk(IMGp(ws, imgN, h, t, 4), dOg + off, 1.f,   tid);
  if (imgN >= 7) {
    gwrow(IMGp(ws, imgN, h, t, 5), q   + off, 1.f, tid);
    gwrow(IMGp(ws, imgN, h, t, 6), dOg + off, 1.f, tid);
  }
}

// NT issue 16KB image -> 2 regs/thread; write regs -> LDS
__device__ __forceinline__ void nt_issue(const ushort* src, int tid, ui4* r) {
  const ui4* s = reinterpret_cast<const ui4*>(src);
  r[0] = __builtin_nontemporal_load(s + tid);
  r[1] = __builtin_nontemporal_load(s + tid + 512);
}
__device__ __forceinline__ void lds_wr(ushort* dst, const ui4* r, int tid) {
  ui4* d = reinterpret_cast<ui4*>(dst);
  d[tid] = r[0];
  d[tid + 512] = r[1];
}

// ---- main kernel: two roles, 128 KB LDS, double-buffered pipeline ---------
// grid 512: xcd(3b) | hpar(1b) | role(1b) | blk(4b)
// role 0: buf[b] at b*24576 {kR,vR,kT}, X at 49152            (2 bars/iter)
// role 1: kR=0 vR=8192 (persistent), qT[b]=16384+b*8192,
//         oT[b]=32768+b*8192, X=49152                          (4 bars/iter)
__global__ void __launch_bounds__(512, 2)
bwd_roles(const float* __restrict__ q, const float* __restrict__ dOg,
          const ushort* __restrict__ ws, const int* __restrict__ mask, int imgN,
          float* __restrict__ dQ, float* __restrict__ dK, float* __restrict__ dV) {
  __shared__ ushort sm[65536];
  ushort* X = sm + 49152;
  const int tid = threadIdx.x;
  const int l = tid & 63, l15 = l & 15, lg = (l >> 4) & 3;
  const int w = tid >> 6, pw = w * 16;
  const int bid = blockIdx.x;
  const int xcd = bid & 7, idx = bid >> 3;
  const int h    = (xcd << 1) | (idx & 1);
  const int role = (idx >> 1) & 1;
  const int blk  = (idx >> 2) & 15;
  const f32x4 zz = {0.f, 0.f, 0.f, 0.f};

  if (role == 0) {
    // ================= dQ for (h, ib = blk) =================
    unsigned bm = 0;
    for (int t = 0; t < TB; ++t)
      if (mask[blk * TB + t]) bm |= 1u << t;

    bf16x8 bq[2], bo[2];   // loop-invariant B-fragments
#pragma unroll
    for (int kb = 0; kb < 2; ++kb) {
      const size_t row = (size_t)(blk * BLK + pw + l15) * DMODEL + h * DKD + kb * 32 + lg * 8;
      bq[kb] = gfrag(q + row, 1.f);
      bo[kb] = gfrag(dOg + row, 1.f);
    }
    f32x4 accQ[4] = {zz, zz, zz, zz};

    if (bm) {
      int j = __ffs(bm) - 1;
      unsigned rest = bm & (bm - 1);
      {
        ui4 t0[2], t1[2], t2[2];
        nt_issue(IMGc(ws, imgN, h, j, 0), tid, t0);
        nt_issue(IMGc(ws, imgN, h, j, 1), tid, t1);
        nt_issue(IMGc(ws, imgN, h, j, 2), tid, t2);
        lds_wr(sm + 0, t0, tid);
        lds_wr(sm + 8192, t1, tid);
        lds_wr(sm + 16384, t2, tid);
      }
      __syncthreads();
      int cur = 0;
      while (j >= 0) {
        const int jn = rest ? (__ffs(rest) - 1) : -1;
        rest = rest ? (rest & (rest - 1)) : 0u;
        ui4 pk0[2], pk1[2], pk2r[2];
        if (jn >= 0) {          // issue next-tile loads before compute
          nt_issue(IMGc(ws, imgN, h, jn, 0), tid, pk0);
          nt_issue(IMGc(ws, imgN, h, jn, 1), tid, pk1);
          nt_issue(IMGc(ws, imgN, h, jn, 2), tid, pk2r);
        }
        const ushort* kR = sm + cur * 24576;
        const ushort* vR = sm + cur * 24576 + 8192;
        const ushort* kT = sm + cur * 24576 + 16384;

        // S^T = k.q^T, dA^T = v.dO^T ; lane: p = pw+l15, c = mf*16+lg*4+r
        f32x4 ST[8], dAT[8];
#pragma unroll
        for (int mf = 0; mf < 8; ++mf) { ST[mf] = zz; dAT[mf] = zz; }
#pragma unroll
        for (int kb = 0; kb < 2; ++kb) {
          const int ck = kb * 32 + lg * 8;
#pragma unroll
          for (int mf = 0; mf < 8; ++mf) {
            ST[mf]  = MFMA(frag64(kR, mf * 16 + l15, ck), bq[kb], ST[mf]);
            dAT[mf] = MFMA(frag64(vR, mf * 16 + l15, ck), bo[kb], dAT[mf]);
          }
        }
        // per-p softmax over 128 c
        float mx = -1e30f;
#pragma unroll
        for (int mf = 0; mf < 8; ++mf)
#pragma unroll
          for (int r = 0; r < 4; ++r) mx = fmaxf(mx, ST[mf][r]);
        mx = fmaxf(mx, __shfl_xor(mx, 16));
        mx = fmaxf(mx, __shfl_xor(mx, 32));
        float ss = 0.f;
#pragma unroll
        for (int mf = 0; mf < 8; ++mf)
#pragma unroll
          for (int r = 0; r < 4; ++r) { const float e = __expf(ST[mf][r] - mx); ST[mf][r] = e; ss += e; }
        ss += __shfl_xor(ss, 16);
        ss += __shfl_xor(ss, 32);
        const float inv = 1.f / (ss + 1e-12f);
        float rd = 0.f;
#pragma unroll
        for (int mf = 0; mf < 8; ++mf)
#pragma unroll
          for (int r = 0; r < 4; ++r) { const float pn = ST[mf][r] * inv; ST[mf][r] = pn; rd += pn * dAT[mf][r]; }
        rd += __shfl_xor(rd, 16);
        rd += __shfl_xor(rd, 32);
#pragma unroll
        for (int mf = 0; mf < 8; ++mf)
#pragma unroll
          for (int r = 0; r < 4; ++r) dAT[mf][r] = ST[mf][r] * (dAT[mf][r] - rd);

        // write dS[p][c] into X (separate region; prev reads fenced by bar2)
        const int p = pw + l15;
#pragma unroll
        for (int mf = 0; mf < 8; ++mf) {
          const ushort2 lo = pk2(dAT[mf][0], dAT[mf][1]);
          const ushort2 hi = pk2(dAT[mf][2], dAT[mf][3]);
          ushort4 u; u.x = lo.x; u.y = lo.y; u.z = hi.x; u.w = hi.y;
          *reinterpret_cast<ushort4*>(X + ((p * 128 + mf * 16 + 4 * lg) ^ ((p & 7) << 3))) = u;
        }
        __syncthreads();                               // bar1: X visible

        // dQ += dS @ k
#pragma unroll
        for (int kc = 0; kc < 4; ++kc) {
          const int cc = kc * 32 + lg * 8;
          const bf16x8 a = frag128(X, pw + l15, cc);
#pragma unroll
          for (int nfd = 0; nfd < 4; ++nfd)
            accQ[nfd] = MFMA(a, fragT2(kT, nfd * 16 + l15, cc), accQ[nfd]);
        }
        if (jn >= 0) {   // write next buffers (no reader until after bar2)
          ushort* nb = sm + (cur ^ 1) * 24576;
          lds_wr(nb, pk0, tid);
          lds_wr(nb + 8192, pk1, tid);
          lds_wr(nb + 16384, pk2r, tid);
        }
        __syncthreads();                               // bar2: bufs ready, X free
        cur ^= 1;
        j = jn;
      }
    }
#pragma unroll
    for (int nfd = 0; nfd < 4; ++nfd)
#pragma unroll
      for (int r = 0; r < 4; ++r)
        __builtin_nontemporal_store(accQ[nfd][r],
            &dQ[(size_t)(blk * BLK + pw + lg * 4 + r) * DMODEL + h * DKD + nfd * 16 + l15]);

  } else {
    // ================= dK, dV for (h, jb = blk) =================
    const int jb = blk;
    unsigned bm = 0;
    for (int t = 0; t < TB; ++t)
      if (mask[t * TB + jb]) bm |= 1u << t;

    f32x4 accK[4] = {zz, zz, zz, zz};
    f32x4 accV[4] = {zz, zz, zz, zz};

    if (bm) {
      const bool hasR = (imgN >= 7);
      int i = __ffs(bm) - 1;
      unsigned rest = bm & (bm - 1);
      bf16x8 aq[2], ao[2];
      {
        ui4 t0[2], t1[2], t2[2], t3[2];
        nt_issue(IMGc(ws, imgN, h, jb, 0), tid, t0);   // kR (reused: normal L2 ok,
        nt_issue(IMGc(ws, imgN, h, jb, 1), tid, t1);   //  but staged once anyway)
        nt_issue(IMGc(ws, imgN, h, i, 3), tid, t2);
        nt_issue(IMGc(ws, imgN, h, i, 4), tid, t3);
        lds_wr(sm + 0, t0, tid);
        lds_wr(sm + 8192, t1, tid);
        lds_wr(sm + 16384, t2, tid);
        lds_wr(sm + 32768, t3, tid);
        if (hasR) {
#pragma unroll
          for (int kb = 0; kb < 2; ++kb) {
            aq[kb] = frag64g(IMGc(ws, imgN, h, i, 5), pw + l15, kb * 32 + lg * 8);
            ao[kb] = frag64g(IMGc(ws, imgN, h, i, 6), pw + l15, kb * 32 + lg * 8);
          }
        } else {
#pragma unroll
          for (int kb = 0; kb < 2; ++kb) {
            const size_t row = (size_t)(i * BLK + pw + l15) * DMODEL + h * DKD + kb * 32 + lg * 8;
            aq[kb] = gfrag(q + row, 1.f);
            ao[kb] = gfrag(dOg + row, 1.f);
          }
        }
      }
      __syncthreads();
      const ushort* kR = sm;
      const ushort* vR = sm + 8192;
      int cur = 0;
      while (i >= 0) {
        const int in = rest ? (__ffs(rest) - 1) : -1;
        rest = rest ? (rest & (rest - 1)) : 0u;
        ui4 pq[2], po[2];
        bf16x8 nq[2], no[2];
        if (in >= 0) {          // issue all next-i loads before compute
          nt_issue(IMGc(ws, imgN, h, in, 3), tid, pq);
          nt_issue(IMGc(ws, imgN, h, in, 4), tid, po);
          if (hasR) {
#pragma unroll
            for (int kb = 0; kb < 2; ++kb) {
              nq[kb] = frag64g(IMGc(ws, imgN, h, in, 5), pw + l15, kb * 32 + lg * 8);
              no[kb] = frag64g(IMGc(ws, imgN, h, in, 6), pw + l15, kb * 32 + lg * 8);
            }
          } else {
#pragma unroll
            for (int kb = 0; kb < 2; ++kb) {
              const size_t row = (size_t)(in * BLK + pw + l15) * DMODEL + h * DKD + kb * 32 + lg * 8;
              nq[kb] = gfrag(q + row, 1.f);
              no[kb] = gfrag(dOg + row, 1.f);
            }
          }
        }
        const ushort* qT = sm + 16384 + cur * 8192;
        const ushort* oT = sm + 32768 + cur * 8192;

        // S = q.k^T, dA = dO.v^T ; lane: p = pw+lg*4+r, c = nf*16+l15
        f32x4 S[8], dA[8];
#pragma unroll
        for (int nf = 0; nf < 8; ++nf) { S[nf] = zz; dA[nf] = zz; }
#pragma unroll
        for (int kb = 0; kb < 2; ++kb) {
          const int ck = kb * 32 + lg * 8;
#pragma unroll
          for (int nf = 0; nf < 8; ++nf) {
            S[nf]  = MFMA(aq[kb], frag64(kR, nf * 16 + l15, ck), S[nf]);
            dA[nf] = MFMA(ao[kb], frag64(vR, nf * 16 + l15, ck), dA[nf]);
          }
        }
        // softmax over c per row; dS = Pn*(dA - rowdot)
#pragma unroll
        for (int r = 0; r < 4; ++r) {
          float mx = -1e30f;
#pragma unroll
          for (int nf = 0; nf < 8; ++nf) mx = fmaxf(mx, S[nf][r]);
          mx = fmaxf(mx, __shfl_xor(mx, 1));
          mx = fmaxf(mx, __shfl_xor(mx, 2));
          mx = fmaxf(mx, __shfl_xor(mx, 4));
          mx = fmaxf(mx, __shfl_xor(mx, 8));
          float ss = 0.f;
#pragma unroll
          for (int nf = 0; nf < 8; ++nf) { const float e = __expf(S[nf][r] - mx); S[nf][r] = e; ss += e; }
          ss += __shfl_xor(ss, 1); ss += __shfl_xor(ss, 2);
          ss += __shfl_xor(ss, 4); ss += __shfl_xor(ss, 8);
          const float inv = 1.f / (ss + 1e-12f);
          float rd = 0.f;
#pragma unroll
          for (int nf = 0; nf < 8; ++nf) { const float pn = S[nf][r] * inv; S[nf][r] = pn; rd += pn * dA[nf][r]; }
          rd += __shfl_xor(rd, 1); rd += __shfl_xor(rd, 2);
          rd += __shfl_xor(rd, 4); rd += __shfl_xor(rd, 8);
#pragma unroll
          for (int nf = 0; nf < 8; ++nf) dA[nf][r] = S[nf][r] * (dA[nf][r] - rd);
        }

        // write Pn^T [c][p] into X
#pragma unroll
        for (int nf = 0; nf < 8; ++nf) {
          const int c = nf * 16 + l15;
          const ushort2 lo = pk2(S[nf][0], S[nf][1]);
          const ushort2 hi = pk2(S[nf][2], S[nf][3]);
          ushort4 u; u.x = lo.x; u.y = lo.y; u.z = hi.x; u.w = hi.y;
          *reinterpret_cast<ushort4*>(X + ((c * 128 + pw + 4 * lg) ^ ((c & 7) << 3))) = u;
        }
        __syncthreads();                               // bar1: PnT visible

        // dV += Pn^T @ dO
#pragma unroll
        for (int kp = 0; kp < 4; ++kp) {
          const int pp = kp * 32 + lg * 8;
          const bf16x8 a = frag128(X, pw + l15, pp);
#pragma unroll
          for (int nfd = 0; nfd < 4; ++nfd)
            accV[nfd] = MFMA(a, fragT2(oT, nfd * 16 + l15, pp), accV[nfd]);
        }
        __syncthreads();                               // bar2: PnT reads done

        // write dS^T [c][p] into X
#pragma unroll
        for (int nf = 0; nf < 8; ++nf) {
          const int c = nf * 16 + l15;
          const ushort2 lo = pk2(dA[nf][0], dA[nf][1]);
          const ushort2 hi = pk2(dA[nf][2], dA[nf][3]);
          ushort4 u; u.x = lo.x; u.y = lo.y; u.z = hi.x; u.w = hi.y;
          *reinterpret_cast<ushort4*>(X + ((c * 128 + pw + 4 * lg) ^ ((c & 7) << 3))) = u;
        }
        __syncthreads();                               // bar3: dST visible

        // dK += dS^T @ q
#pragma unroll
        for (int kp = 0; kp < 4; ++kp) {
          const int pp = kp * 32 + lg * 8;
          const bf16x8 a = frag128(X, pw + l15, pp);
#pragma unroll
          for (int nfd = 0; nfd < 4; ++nfd)
            accK[nfd] = MFMA(a, fragT2(qT, nfd * 16 + l15, pp), accK[nfd]);
        }
        if (in >= 0) {    // write next qT/oT buffers; carry next A-frags
          lds_wr(sm + 16384 + (cur ^ 1) * 8192, pq, tid);
          lds_wr(sm + 32768 + (cur ^ 1) * 8192, po, tid);
          aq[0] = nq[0]; aq[1] = nq[1];
          ao[0] = no[0]; ao[1] = no[1];
        }
        __syncthreads();                               // bar4: bufs ready, X free
        cur ^= 1;
        i = in;
      }
    }
#pragma unroll
    for (int nfd = 0; nfd < 4; ++nfd)
#pragma unroll
      for (int r = 0; r < 4; ++r) {
        const size_t rowo = (size_t)(jb * BLK + pw + lg * 4 + r) * DMODEL + h * DKD + nfd * 16 + l15;
        __builtin_nontemporal_store(accK[nfd][r], &dK[rowo]);
        __builtin_nontemporal_store(accV[nfd][r], &dV[rowo]);
      }
  }
}

extern "C" void kernel_launch(void* const* d_in, const int* in_sizes, int n_in,
                              void* d_out, int out_size, void* d_ws, size_t ws_size,
                              hipStream_t stream) {
  const float* q  = (const float*)d_in[0];
  const float* k  = (const float*)d_in[1];
  const float* v  = (const float*)d_in[2];
  const float* dO = (const float*)d_in[3];
  const int* mask = (const int*)d_in[4];
  float* out = (float*)d_out;
  float* dQ = out;
  float* dK = out + (size_t)2048 * DMODEL;
  float* dV = out + (size_t)2 * 2048 * DMODEL;
  ushort* ws = (ushort*)d_ws;

  const size_t need7 = (size_t)NHEAD * TB * 7 * 16384;  // 28.7 MB
  const int imgN = (ws_size >= need7) ? 7 : 5;

  prepass<<<NHEAD * TB, 512, 0, stream>>>(q, k, v, dO, ws, imgN);
  bwd_roles<<<2 * NHEAD * TB, 512, 0, stream>>>(q, dO, ws, mask, imgN, dQ, dK, dV);
}

// Round 12
// 119.742 us; speedup vs baseline: 2.2391x; 1.0058x over previous
//
#include <hip/hip_runtime.h>
#include <hip/hip_bf16.h>

#define DMODEL 1024
#define NHEAD  16
#define DKD    64
#define BLK    128
#define TB     16
#define SCALEF 0.125f   // TAU / sqrt(DK)

typedef __attribute__((ext_vector_type(8))) short bf16x8;
typedef __attribute__((ext_vector_type(4))) _Float16 f16x4;
typedef __attribute__((ext_vector_type(4))) float f32x4;
typedef __attribute__((ext_vector_type(4))) unsigned int ui4;

#define MFMA(A, B, C)   __builtin_amdgcn_mfma_f32_16x16x32_bf16(A, B, C, 0, 0, 0)
#define MFMA16(A, B, C) __builtin_amdgcn_mfma_f32_16x16x16f16(A, B, C, 0, 0, 0)

union U8 { bf16x8 v; ushort u[8]; ushort2 u2[4]; ushort4 u4[2]; };

__device__ __forceinline__ ushort2 pk2(float a, float b) {
  union { __hip_bfloat162 h; ushort2 u; } c;
  c.h = __float22bfloat162_rn(make_float2(a, b));
  return c.u;
}
__device__ __forceinline__ ushort4 pkh4(float a, float b, float c, float d) {
  union { f16x4 h; ushort4 u; } z;
  z.h[0] = (_Float16)a; z.h[1] = (_Float16)b;
  z.h[2] = (_Float16)c; z.h[3] = (_Float16)d;
  return z.u;
}

// ---- tile-image readers (R2/R6/R7-proven formulas) -----------------------
// row tile [128][64] bf16, XOR-swizzled by ((r&7)<<3)
__device__ __forceinline__ bf16x8 frag64(const ushort* T, int r, int c) {
  return *reinterpret_cast<const bf16x8*>(T + ((r * 64 + c) ^ ((r & 7) << 3)));
}
__device__ __forceinline__ bf16x8 frag64g(const ushort* T, int r, int c) {
  return __builtin_nontemporal_load(
      reinterpret_cast<const bf16x8*>(T + ((r * 64 + c) ^ ((r & 7) << 3))));
}
// [128][128] bf16 tile, same swizzle
__device__ __forceinline__ bf16x8 frag128(const ushort* T, int r, int c) {
  return *reinterpret_cast<const bf16x8*>(T + ((r * 128 + c) ^ ((r & 7) << 3)));
}
// chunked transposed tile [64 d][128 r]: elem (d,r) at
// (r>>2)*256 + ((d*4) ^ (((d>>4)&3)<<2)) + (r&3)  -- b128 reads for mfma32
__device__ __forceinline__ bf16x8 fragT2(const ushort* T, int d, int r0) {
  const int base = (r0 >> 2) * 256 + ((d * 4) ^ (((d >> 4) & 3) << 2));
  U8 x;
  x.u4[0] = *reinterpret_cast<const ushort4*>(T + base);
  x.u4[1] = *reinterpret_cast<const ushort4*>(T + base + 256);
  return x.v;
}
// K=16 A-frag from fp16 chunked tile: lane needs elems (d, r = g*4+{0..3}),
// g = mf*4+lg -> one aligned b64 read
__device__ __forceinline__ f16x4 fragK16(const ushort* T, int d, int g) {
  union { ushort4 u; f16x4 h; } z;
  z.u = *reinterpret_cast<const ushort4*>(T + g * 256 + ((d * 4) ^ (((d >> 4) & 3) << 2)));
  return z.h;
}
// global fp32 row-major -> bf16 register fragment
__device__ __forceinline__ bf16x8 gfrag(const float* __restrict__ g, float sc) {
  const float4 fa = *reinterpret_cast<const float4*>(g);
  const float4 fb = *reinterpret_cast<const float4*>(g + 4);
  U8 x;
  x.u2[0] = pk2(fa.x * sc, fa.y * sc);
  x.u2[1] = pk2(fa.z * sc, fa.w * sc);
  x.u2[2] = pk2(fb.x * sc, fb.y * sc);
  x.u2[3] = pk2(fb.z * sc, fb.w * sc);
  return x.v;
}

// ---- prepass image writers (512 threads) ---------------------------------
__device__ __forceinline__ void gwrow(ushort* T, const float* __restrict__ g,
                                      float sc, int tid) {
#pragma unroll
  for (int it = 0; it < 4; ++it) {
    const int idx = tid + 512 * it;
    const int r = idx >> 4, d4 = idx & 15;
    const float4 f = *reinterpret_cast<const float4*>(g + r * DMODEL + 4 * d4);
    const ushort2 lo = pk2(f.x * sc, f.y * sc);
    const ushort2 hi = pk2(f.z * sc, f.w * sc);
    ushort4 u; u.x = lo.x; u.y = lo.y; u.z = hi.x; u.w = hi.y;
    *reinterpret_cast<ushort4*>(T + ((r * 64 + 4 * d4) ^ ((r & 7) << 3))) = u;
  }
}
// shfl butterfly transpose -> chunked tile; HALF=1 writes fp16 payload
template <int HALF>
__device__ __forceinline__ void gwchunk(ushort* T, const float* __restrict__ g,
                                        float sc, int tid) {
  const int a = (tid >> 4) & 3;
#pragma unroll
  for (int it = 0; it < 4; ++it) {
    const int idx = tid + 512 * it;
    const int r = idx >> 4, d4 = idx & 15;
    const float4 f = *reinterpret_cast<const float4*>(g + r * DMODEL + 4 * d4);
    const float w0 = f.x * sc, w1 = f.y * sc, w2 = f.z * sc, w3 = f.w * sc;
    const float s0 = __shfl_xor(w1, 16), s1 = __shfl_xor(w0, 16);
    const float s2 = __shfl_xor(w3, 16), s3 = __shfl_xor(w2, 16);
    const float u0 = (a & 1) ? s0 : w0;
    const float u1 = (a & 1) ? w1 : s1;
    const float u2 = (a & 1) ? s2 : w2;
    const float u3 = (a & 1) ? w3 : s3;
    const float t0 = __shfl_xor(u2, 32), t1 = __shfl_xor(u3, 32);
    const float t2 = __shfl_xor(u0, 32), t3 = __shfl_xor(u1, 32);
    const float z0 = (a & 2) ? t0 : u0;
    const float z1 = (a & 2) ? t1 : u1;
    const float z2 = (a & 2) ? u2 : t2;
    const float z3 = (a & 2) ? u3 : t3;
    const int d = 4 * d4 + a, R0 = r - a;   // lane holds rows R0..R0+3 of col d
    ushort4 o;
    if constexpr (HALF) {
      o = pkh4(z0, z1, z2, z3);
    } else {
      const ushort2 lo = pk2(z0, z1);
      const ushort2 hi = pk2(z2, z3);
      o.x = lo.x; o.y = lo.y; o.z = hi.x; o.w = hi.y;
    }
    *reinterpret_cast<ushort4*>(T + (R0 >> 2) * 256 + ((d * 4) ^ (((d >> 4) & 3) << 2))) = o;
  }
}

// images per (h,t): 0 KR(bf16,k*scale) 1 VR(bf16,v) 2 KT16(fp16,k*scale)
//                   3 QT(bf16,q*scale) 4 OT(bf16,dO) 5 QR(bf16,q) 6 OR(bf16,dO)
__device__ __forceinline__ ushort* IMGp(ushort* ws, int imgN, int h, int t, int i) {
  return ws + (((size_t)h * TB + t) * imgN + i) * 8192;
}
__device__ __forceinline__ const ushort* IMGc(const ushort* ws, int imgN, int h, int t, int i) {
  return ws + (((size_t)h * TB + t) * imgN + i) * 8192;
}

__global__ void __launch_bounds__(512, 2)
prepass(const float* __restrict__ q, const float* __restrict__ kk,
        const float* __restrict__ v, const float* __restrict__ dOg,
        ushort* __restrict__ ws, int imgN) {
  const int bid = blockIdx.x;          // 256 = h*16 + t
  const int h = bid >> 4, t = bid & 15;
  const int tid = threadIdx.x;
  const size_t off = (size_t)(t * BLK) * DMODEL + h * DKD;
  gwrow     (IMGp(ws, imgN, h, t, 0), kk + off, SCALEF, tid);
  gwrow     (IMGp(ws, imgN, h, t, 1), v  + off, 1.f,    tid);
  gwchunk<1>(IMGp(ws, imgN, h, t, 2), kk + off, SCALEF, tid);
  gwchunk<0>(IMGp(ws, imgN, h, t, 3), q  + off, SCALEF, tid);
  gwchunk<0>(IMGp(ws, imgN, h, t, 4), dOg + off, 1.f,   tid);
  if (imgN >= 7) {
    gwrow(IMGp(ws, imgN, h, t, 5), q   + off, 1.f, tid);
    gwrow(IMGp(ws, imgN, h, t, 6), dOg + off, 1.f, tid);
  }
}

__device__ __forceinline__ void nt_issue(const ushort* src, int tid, ui4* r) {
  const ui4* s = reinterpret_cast<const ui4*>(src);
  r[0] = __builtin_nontemporal_load(s + tid);
  r[1] = __builtin_nontemporal_load(s + tid + 512);
}
__device__ __forceinline__ void lds_wr(ushort* dst, const ui4* r, int tid) {
  ui4* d = reinterpret_cast<ui4*>(dst);
  d[tid] = r[0];
  d[tid + 512] = r[1];
}

// ---- main kernel: 128 KB LDS, role0 = 1 bar/iter, role1 = 2 bars/iter -----
// grid 512: xcd(3b) | hpar(1b) | role(1b) | blk(4b)
// role 0: buf[b] at b*24576 {kR, vR, kT16}                (X-free dQ via K=16)
// role 1: kR=0 vR=8192 qT=16384 oT=24576 X1=32768 X2=49152
__global__ void __launch_bounds__(512, 1)
bwd_roles(const float* __restrict__ q, const float* __restrict__ dOg,
          const ushort* __restrict__ ws, const int* __restrict__ mask, int imgN,
          float* __restrict__ dQ, float* __restrict__ dK, float* __restrict__ dV) {
  __shared__ ushort sm[65536];
  const int tid = threadIdx.x;
  const int l = tid & 63, l15 = l & 15, lg = (l >> 4) & 3;
  const int w = tid >> 6, pw = w * 16;
  const int bid = blockIdx.x;
  const int xcd = bid & 7, idx = bid >> 3;
  const int h    = (xcd << 1) | (idx & 1);
  const int role = (idx >> 1) & 1;
  const int blk  = (idx >> 2) & 15;
  const f32x4 zz = {0.f, 0.f, 0.f, 0.f};

  if (role == 0) {
    // ================= dQ for (h, ib = blk), 1 barrier/iter =================
    unsigned bm = 0;
    for (int t = 0; t < TB; ++t)
      if (mask[blk * TB + t]) bm |= 1u << t;

    bf16x8 bq[2], bo[2];   // loop-invariant B-fragments (q, dO rows)
#pragma unroll
    for (int kb = 0; kb < 2; ++kb) {
      const size_t row = (size_t)(blk * BLK + pw + l15) * DMODEL + h * DKD + kb * 32 + lg * 8;
      bq[kb] = gfrag(q + row, 1.f);
      bo[kb] = gfrag(dOg + row, 1.f);
    }
    f32x4 accQT[4] = {zz, zz, zz, zz};   // dQ^T[d = df*16+lg*4+r][p = pw+l15]

    if (bm) {
      int j = __ffs(bm) - 1;
      unsigned rest = bm & (bm - 1);
      {
        ui4 t0[2], t1[2], t2[2];
        nt_issue(IMGc(ws, imgN, h, j, 0), tid, t0);
        nt_issue(IMGc(ws, imgN, h, j, 1), tid, t1);
        nt_issue(IMGc(ws, imgN, h, j, 2), tid, t2);
        lds_wr(sm + 0, t0, tid);
        lds_wr(sm + 8192, t1, tid);
        lds_wr(sm + 16384, t2, tid);
      }
      __syncthreads();
      int cur = 0;
      while (j >= 0) {
        const int jn = rest ? (__ffs(rest) - 1) : -1;
        rest = rest ? (rest & (rest - 1)) : 0u;
        ui4 pk0[2], pk1[2], pk2r[2];
        if (jn >= 0) {          // issue next-tile loads before compute
          nt_issue(IMGc(ws, imgN, h, jn, 0), tid, pk0);
          nt_issue(IMGc(ws, imgN, h, jn, 1), tid, pk1);
          nt_issue(IMGc(ws, imgN, h, jn, 2), tid, pk2r);
        }
        const ushort* kR = sm + cur * 24576;
        const ushort* vR = sm + cur * 24576 + 8192;
        const ushort* kT = sm + cur * 24576 + 16384;

        // S^T = k.q^T, dA^T = v.dO^T ; lane: p = pw+l15, c = mf*16+lg*4+r
        f32x4 ST[8], dAT[8];
#pragma unroll
        for (int mf = 0; mf < 8; ++mf) { ST[mf] = zz; dAT[mf] = zz; }
#pragma unroll
        for (int kb = 0; kb < 2; ++kb) {
          const int ck = kb * 32 + lg * 8;
#pragma unroll
          for (int mf = 0; mf < 8; ++mf) {
            ST[mf]  = MFMA(frag64(kR, mf * 16 + l15, ck), bq[kb], ST[mf]);
            dAT[mf] = MFMA(frag64(vR, mf * 16 + l15, ck), bo[kb], dAT[mf]);
          }
        }
        // per-p softmax over 128 c (regs + lanes l^16, l^32)
        float mx = -1e30f;
#pragma unroll
        for (int mf = 0; mf < 8; ++mf)
#pragma unroll
          for (int r = 0; r < 4; ++r) mx = fmaxf(mx, ST[mf][r]);
        mx = fmaxf(mx, __shfl_xor(mx, 16));
        mx = fmaxf(mx, __shfl_xor(mx, 32));
        float ss = 0.f;
#pragma unroll
        for (int mf = 0; mf < 8; ++mf)
#pragma unroll
          for (int r = 0; r < 4; ++r) { const float e = __expf(ST[mf][r] - mx); ST[mf][r] = e; ss += e; }
        ss += __shfl_xor(ss, 16);
        ss += __shfl_xor(ss, 32);
        const float inv = 1.f / (ss + 1e-12f);
        float rd = 0.f;
#pragma unroll
        for (int mf = 0; mf < 8; ++mf)
#pragma unroll
          for (int r = 0; r < 4; ++r) { const float pn = ST[mf][r] * inv; ST[mf][r] = pn; rd += pn * dAT[mf][r]; }
        rd += __shfl_xor(rd, 16);
        rd += __shfl_xor(rd, 32);

        // dS in regs -> fp16 B-frags (k = lg*4+i matches K=16 B layout)
        f16x4 pb[8];
#pragma unroll
        for (int mf = 0; mf < 8; ++mf) {
#pragma unroll
          for (int r = 0; r < 4; ++r)
            pb[mf][r] = (_Float16)(ST[mf][r] * (dAT[mf][r] - rd));
        }
        // dQ^T[d][p] += sum_c kT[d][c] * dS[p][c]   (32x mfma 16x16x16 f16)
#pragma unroll
        for (int df = 0; df < 4; ++df)
#pragma unroll
          for (int mf = 0; mf < 8; ++mf)
            accQT[df] = MFMA16(fragK16(kT, df * 16 + l15, mf * 4 + lg), pb[mf], accQT[df]);

        if (jn >= 0) {   // write next buffers (no reader until after bar)
          ushort* nb = sm + (cur ^ 1) * 24576;
          lds_wr(nb, pk0, tid);
          lds_wr(nb + 8192, pk1, tid);
          lds_wr(nb + 16384, pk2r, tid);
        }
        __syncthreads();   // single barrier: next buf visible + cur free
        cur ^= 1;
        j = jn;
      }
    }
    // epilogue: lane holds dQ^T[df*16+lg*4+r][pw+l15] -> f32x4 row store
#pragma unroll
    for (int df = 0; df < 4; ++df) {
      f32x4 wv;
      wv[0] = accQT[df][0]; wv[1] = accQT[df][1];
      wv[2] = accQT[df][2]; wv[3] = accQT[df][3];
      __builtin_nontemporal_store(wv, reinterpret_cast<f32x4*>(
          dQ + (size_t)(blk * BLK + pw + l15) * DMODEL + h * DKD + df * 16 + lg * 4));
    }

  } else {
    // ================= dK, dV for (h, jb = blk), 2 barriers/iter ============
    const int jb = blk;
    unsigned bm = 0;
    for (int t = 0; t < TB; ++t)
      if (mask[t * TB + jb]) bm |= 1u << t;

    f32x4 accK[4] = {zz, zz, zz, zz};
    f32x4 accV[4] = {zz, zz, zz, zz};

    if (bm) {
      const bool hasR = (imgN >= 7);
      ushort* kR = sm;
      ushort* vR = sm + 8192;
      ushort* qT = sm + 16384;
      ushort* oT = sm + 24576;
      ushort* X1 = sm + 32768;
      ushort* X2 = sm + 49152;
      int i = __ffs(bm) - 1;
      unsigned rest = bm & (bm - 1);
      bf16x8 aq[2], ao[2];
      {
        ui4 t0[2], t1[2], t2[2], t3[2];
        nt_issue(IMGc(ws, imgN, h, jb, 0), tid, t0);
        nt_issue(IMGc(ws, imgN, h, jb, 1), tid, t1);
        nt_issue(IMGc(ws, imgN, h, i, 3), tid, t2);
        nt_issue(IMGc(ws, imgN, h, i, 4), tid, t3);
        lds_wr(kR, t0, tid);
        lds_wr(vR, t1, tid);
        lds_wr(qT, t2, tid);
        lds_wr(oT, t3, tid);
        if (hasR) {
#pragma unroll
          for (int kb = 0; kb < 2; ++kb) {
            aq[kb] = frag64g(IMGc(ws, imgN, h, i, 5), pw + l15, kb * 32 + lg * 8);
            ao[kb] = frag64g(IMGc(ws, imgN, h, i, 6), pw + l15, kb * 32 + lg * 8);
          }
        } else {
#pragma unroll
          for (int kb = 0; kb < 2; ++kb) {
            const size_t row = (size_t)(i * BLK + pw + l15) * DMODEL + h * DKD + kb * 32 + lg * 8;
            aq[kb] = gfrag(q + row, 1.f);
            ao[kb] = gfrag(dOg + row, 1.f);
          }
        }
      }
      __syncthreads();

      while (i >= 0) {
        const int in = rest ? (__ffs(rest) - 1) : -1;
        rest = rest ? (rest & (rest - 1)) : 0u;
        ui4 pq[2], po[2];
        bf16x8 nq[2], no[2];
        if (in >= 0) {          // issue all next-i loads before compute
          nt_issue(IMGc(ws, imgN, h, in, 3), tid, pq);
          nt_issue(IMGc(ws, imgN, h, in, 4), tid, po);
          if (hasR) {
#pragma unroll
            for (int kb = 0; kb < 2; ++kb) {
              nq[kb] = frag64g(IMGc(ws, imgN, h, in, 5), pw + l15, kb * 32 + lg * 8);
              no[kb] = frag64g(IMGc(ws, imgN, h, in, 6), pw + l15, kb * 32 + lg * 8);
            }
          } else {
#pragma unroll
            for (int kb = 0; kb < 2; ++kb) {
              const size_t row = (size_t)(in * BLK + pw + l15) * DMODEL + h * DKD + kb * 32 + lg * 8;
              nq[kb] = gfrag(q + row, 1.f);
              no[kb] = gfrag(dOg + row, 1.f);
            }
          }
        }

        // S = q.k^T, dA = dO.v^T ; lane: p = pw+lg*4+r, c = nf*16+l15
        f32x4 S[8], dA[8];
#pragma unroll
        for (int nf = 0; nf < 8; ++nf) { S[nf] = zz; dA[nf] = zz; }
#pragma unroll
        for (int kb = 0; kb < 2; ++kb) {
          const int ck = kb * 32 + lg * 8;
#pragma unroll
          for (int nf = 0; nf < 8; ++nf) {
            S[nf]  = MFMA(aq[kb], frag64(kR, nf * 16 + l15, ck), S[nf]);
            dA[nf] = MFMA(ao[kb], frag64(vR, nf * 16 + l15, ck), dA[nf]);
          }
        }
        // softmax over c per row; dS = Pn*(dA - rowdot)
#pragma unroll
        for (int r = 0; r < 4; ++r) {
          float mx = -1e30f;
#pragma unroll
          for (int nf = 0; nf < 8; ++nf) mx = fmaxf(mx, S[nf][r]);
          mx = fmaxf(mx, __shfl_xor(mx, 1));
          mx = fmaxf(mx, __shfl_xor(mx, 2));
          mx = fmaxf(mx, __shfl_xor(mx, 4));
          mx = fmaxf(mx, __shfl_xor(mx, 8));
          float ss = 0.f;
#pragma unroll
          for (int nf = 0; nf < 8; ++nf) { const float e = __expf(S[nf][r] - mx); S[nf][r] = e; ss += e; }
          ss += __shfl_xor(ss, 1); ss += __shfl_xor(ss, 2);
          ss += __shfl_xor(ss, 4); ss += __shfl_xor(ss, 8);
          const float inv = 1.f / (ss + 1e-12f);
          float rd = 0.f;
#pragma unroll
          for (int nf = 0; nf < 8; ++nf) { const float pn = S[nf][r] * inv; S[nf][r] = pn; rd += pn * dA[nf][r]; }
          rd += __shfl_xor(rd, 1); rd += __shfl_xor(rd, 2);
          rd += __shfl_xor(rd, 4); rd += __shfl_xor(rd, 8);
#pragma unroll
          for (int nf = 0; nf < 8; ++nf) dA[nf][r] = S[nf][r] * (dA[nf][r] - rd);
        }

        // write Pn^T -> X1 and dS^T -> X2 together ([c][p], b64 packs)
#pragma unroll
        for (int nf = 0; nf < 8; ++nf) {
          const int c = nf * 16 + l15;
          const int off = (c * 128 + pw + 4 * lg) ^ ((c & 7) << 3);
          {
            const ushort2 lo = pk2(S[nf][0], S[nf][1]);
            const ushort2 hi = pk2(S[nf][2], S[nf][3]);
            ushort4 u; u.x = lo.x; u.y = lo.y; u.z = hi.x; u.w = hi.y;
            *reinterpret_cast<ushort4*>(X1 + off) = u;
          }
          {
            const ushort2 lo = pk2(dA[nf][0], dA[nf][1]);
            const ushort2 hi = pk2(dA[nf][2], dA[nf][3]);
            ushort4 u; u.x = lo.x; u.y = lo.y; u.z = hi.x; u.w = hi.y;
            *reinterpret_cast<ushort4*>(X2 + off) = u;
          }
        }
        __syncthreads();                 // bar_a: X1/X2 visible; qT/oT (new) visible

        // dV += Pn^T @ dO ; dK += dS^T @ q
#pragma unroll
        for (int kp = 0; kp < 4; ++kp) {
          const int pp = kp * 32 + lg * 8;
          const bf16x8 a1 = frag128(X1, pw + l15, pp);
          const bf16x8 a2 = frag128(X2, pw + l15, pp);
#pragma unroll
          for (int nfd = 0; nfd < 4; ++nfd) {
            accV[nfd] = MFMA(a1, fragT2(oT, nfd * 16 + l15, pp), accV[nfd]);
            accK[nfd] = MFMA(a2, fragT2(qT, nfd * 16 + l15, pp), accK[nfd]);
          }
        }
        __syncthreads();                 // bar_b: qT/oT reads done; X reads done

        if (in >= 0) {   // write next qT/oT (readers wait behind next bar_a)
          lds_wr(qT, pq, tid);
          lds_wr(oT, po, tid);
          aq[0] = nq[0]; aq[1] = nq[1];
          ao[0] = no[0]; ao[1] = no[1];
        }
        i = in;
      }
    }
#pragma unroll
    for (int nfd = 0; nfd < 4; ++nfd)
#pragma unroll
      for (int r = 0; r < 4; ++r) {
        const size_t rowo = (size_t)(jb * BLK + pw + lg * 4 + r) * DMODEL + h * DKD + nfd * 16 + l15;
        __builtin_nontemporal_store(accK[nfd][r], &dK[rowo]);
        __builtin_nontemporal_store(accV[nfd][r], &dV[rowo]);
      }
  }
}

extern "C" void kernel_launch(void* const* d_in, const int* in_sizes, int n_in,
                              void* d_out, int out_size, void* d_ws, size_t ws_size,
                              hipStream_t stream) {
  const float* q  = (const float*)d_in[0];
  const float* k  = (const float*)d_in[1];
  const float* v  = (const float*)d_in[2];
  const float* dO = (const float*)d_in[3];
  const int* mask = (const int*)d_in[4];
  float* out = (float*)d_out;
  float* dQ = out;
  float* dK = out + (size_t)2048 * DMODEL;
  float* dV = out + (size_t)2 * 2048 * DMODEL;
  ushort* ws = (ushort*)d_ws;

  const size_t need7 = (size_t)NHEAD * TB * 7 * 16384;  // 28.7 MB
  const int imgN = (ws_size >= need7) ? 7 : 5;

  prepass<<<NHEAD * TB, 512, 0, stream>>>(q, k, v, dO, ws, imgN);
  bwd_roles<<<2 * NHEAD * TB, 512, 0, stream>>>(q, dO, ws, mask, imgN, dQ, dK, dV);
}